// Round 1
// baseline (3949.603 us; speedup 1.0000x reference)
//
#include <hip/hip_runtime.h>
#include <math.h>

#define DIM   512
#define CDIM  128
#define CSIZE 8192
#define NTOK  16384          // 4 * 4096
#define EPSV  1e-6f

#define SELU_SCALE 1.0507009873554805f
#define SELU_ALPHA 1.6732632423543772f

__device__ __forceinline__ float selu_f(float v) {
    return SELU_SCALE * (v > 0.f ? v : SELU_ALPHA * expm1f(v));
}

// ---------------------------------------------------------------- zero / fin
__global__ void k_zero(float* __restrict__ acc) { acc[0] = 0.f; }

__global__ void k_fin(const float* __restrict__ acc, float* __restrict__ out_loss) {
    // commit_loss = mean((x-q)^2) + 0.25*mean((x-q)^2) = 1.25 * mean
    out_loss[0] = 1.25f * acc[0] / (float)((size_t)NTOK * DIM);
}

// ---------------------------------------------------------------- GEMM1: h = cb@W1 + b1
// cb [CSIZE,CDIM], W1 [CDIM,DIM], h [CSIZE,DIM]
__global__ __launch_bounds__(256) void k_gemm1(const float* __restrict__ cb,
                                               const float* __restrict__ W1,
                                               const float* __restrict__ b1,
                                               float* __restrict__ h) {
    __shared__ float a_t[32][68];   // a_t[k][m] = cb[m0+m][k0+k]
    __shared__ float b_t[32][68];   // b_t[k][n] = W1[k0+k][n0+n]
    const int m0 = blockIdx.x * 64;
    const int n0 = blockIdx.y * 64;
    const int tid = threadIdx.x;
    const int tx = tid & 15, ty = tid >> 4;
    float acc[4][4] = {};
    for (int k0 = 0; k0 < CDIM; k0 += 32) {
        for (int l = tid; l < 64 * 32; l += 256) {
            int m = l >> 5, kk = l & 31;
            a_t[kk][m] = cb[(size_t)(m0 + m) * CDIM + k0 + kk];
        }
        for (int l = tid; l < 32 * 64; l += 256) {
            int kk = l >> 6, nn = l & 63;
            b_t[kk][nn] = W1[(size_t)(k0 + kk) * DIM + n0 + nn];
        }
        __syncthreads();
#pragma unroll
        for (int kk = 0; kk < 32; ++kk) {
            const float4 av = *(const float4*)&a_t[kk][ty * 4];
            const float4 bv = *(const float4*)&b_t[kk][tx * 4];
            float a[4] = {av.x, av.y, av.z, av.w};
            float b[4] = {bv.x, bv.y, bv.z, bv.w};
#pragma unroll
            for (int i = 0; i < 4; ++i)
#pragma unroll
                for (int j = 0; j < 4; ++j)
                    acc[i][j] = fmaf(a[i], b[j], acc[i][j]);
        }
        __syncthreads();
    }
#pragma unroll
    for (int i = 0; i < 4; ++i) {
        const int m = m0 + ty * 4 + i;
#pragma unroll
        for (int j = 0; j < 4; ++j) {
            const int n = n0 + tx * 4 + j;
            h[(size_t)m * DIM + n] = acc[i][j] + b1[n];
        }
    }
}

// ---------------------------------------------------------------- GEMM2: icb = h + selu(h)@W2 + b2
__global__ __launch_bounds__(256) void k_gemm2(const float* __restrict__ h,
                                               const float* __restrict__ W2,
                                               const float* __restrict__ b2,
                                               float* __restrict__ icb) {
    __shared__ float a_t[32][68];   // selu(h) transposed tile
    __shared__ float b_t[32][68];   // W2 tile
    const int m0 = blockIdx.x * 64;
    const int n0 = blockIdx.y * 64;
    const int tid = threadIdx.x;
    const int tx = tid & 15, ty = tid >> 4;
    float acc[4][4] = {};
    for (int k0 = 0; k0 < DIM; k0 += 32) {
        for (int l = tid; l < 64 * 32; l += 256) {
            int m = l >> 5, kk = l & 31;
            a_t[kk][m] = selu_f(h[(size_t)(m0 + m) * DIM + k0 + kk]);
        }
        for (int l = tid; l < 32 * 64; l += 256) {
            int kk = l >> 6, nn = l & 63;
            b_t[kk][nn] = W2[(size_t)(k0 + kk) * DIM + n0 + nn];
        }
        __syncthreads();
#pragma unroll
        for (int kk = 0; kk < 32; ++kk) {
            const float4 av = *(const float4*)&a_t[kk][ty * 4];
            const float4 bv = *(const float4*)&b_t[kk][tx * 4];
            float a[4] = {av.x, av.y, av.z, av.w};
            float b[4] = {bv.x, bv.y, bv.z, bv.w};
#pragma unroll
            for (int i = 0; i < 4; ++i)
#pragma unroll
                for (int j = 0; j < 4; ++j)
                    acc[i][j] = fmaf(a[i], b[j], acc[i][j]);
        }
        __syncthreads();
    }
#pragma unroll
    for (int i = 0; i < 4; ++i) {
        const int m = m0 + ty * 4 + i;
#pragma unroll
        for (int j = 0; j < 4; ++j) {
            const int n = n0 + tx * 4 + j;
            icb[(size_t)m * DIM + n] = acc[i][j] + h[(size_t)m * DIM + n] + b2[n];
        }
    }
}

// ---------------------------------------------------------------- code norms: rn2[c] = sum_d icb[c][d]^2
__global__ __launch_bounds__(256) void k_rn2(const float* __restrict__ icb,
                                             float* __restrict__ rn2) {
    const int row  = blockIdx.x * 4 + (threadIdx.x >> 6);
    const int lane = threadIdx.x & 63;
    const float4* p = (const float4*)(icb + (size_t)row * DIM);
    float s = 0.f;
#pragma unroll
    for (int it = 0; it < DIM / 4 / 64; ++it) {
        float4 v = p[lane + 64 * it];
        s += v.x * v.x + v.y * v.y + v.z * v.z + v.w * v.w;
    }
#pragma unroll
    for (int o = 32; o > 0; o >>= 1) s += __shfl_xor(s, o);
    if (lane == 0) rn2[row] = s;
}

// ---------------------------------------------------------------- distance + partial argmin
// Each block: 64 tokens x 2048 codes (code-split = blockIdx.y of 4).
// Tile: TN=128 codes in flight, K-tiles of 32. Thread tile 4 tokens x 8 codes.
__global__ __launch_bounds__(256) void k_dist(const float* __restrict__ x,
                                              const float* __restrict__ icb,
                                              const float* __restrict__ rn2,
                                              float* __restrict__ pval,
                                              int*   __restrict__ pidx) {
    __shared__ float x_t[32][68];    // x_t[k][m]
    __shared__ float c_t[32][132];   // c_t[k][n], n < 128
    const int m0 = blockIdx.x * 64;
    const int cs = blockIdx.y;                 // 0..3
    const int tid = threadIdx.x;
    const int tx = tid & 15, ty = tid >> 4;
    float best[4];
    int   bidx[4];
#pragma unroll
    for (int i = 0; i < 4; ++i) { best[i] = 3.0e38f; bidx[i] = 0; }

    const int c_begin = cs * (CSIZE / 4);
    for (int n0 = c_begin; n0 < c_begin + CSIZE / 4; n0 += 128) {
        float acc[4][8] = {};
        for (int k0 = 0; k0 < DIM; k0 += 32) {
            for (int l = tid; l < 64 * 32; l += 256) {
                int m = l >> 5, kk = l & 31;
                x_t[kk][m] = x[(size_t)(m0 + m) * DIM + k0 + kk];
            }
            for (int l = tid; l < 128 * 32; l += 256) {
                int n = l >> 5, kk = l & 31;
                c_t[kk][n] = icb[(size_t)(n0 + n) * DIM + k0 + kk];
            }
            __syncthreads();
#pragma unroll
            for (int kk = 0; kk < 32; ++kk) {
                const float4 av  = *(const float4*)&x_t[kk][ty * 4];
                const float4 bv0 = *(const float4*)&c_t[kk][tx * 8];
                const float4 bv1 = *(const float4*)&c_t[kk][tx * 8 + 4];
                float a[4] = {av.x, av.y, av.z, av.w};
                float b[8] = {bv0.x, bv0.y, bv0.z, bv0.w, bv1.x, bv1.y, bv1.z, bv1.w};
#pragma unroll
                for (int i = 0; i < 4; ++i)
#pragma unroll
                    for (int j = 0; j < 8; ++j)
                        acc[i][j] = fmaf(a[i], b[j], acc[i][j]);
            }
            __syncthreads();
        }
        // fold this code chunk into running best (d2 minus per-token ||x||^2 const)
        const float4 r0 = *(const float4*)&rn2[n0 + tx * 8];
        const float4 r1 = *(const float4*)&rn2[n0 + tx * 8 + 4];
        float r[8] = {r0.x, r0.y, r0.z, r0.w, r1.x, r1.y, r1.z, r1.w};
#pragma unroll
        for (int i = 0; i < 4; ++i) {
            float v = r[0] - 2.f * acc[i][0];
            int   id = n0 + tx * 8;
#pragma unroll
            for (int j = 1; j < 8; ++j) {
                float vj = r[j] - 2.f * acc[i][j];
                if (vj < v) { v = vj; id = n0 + tx * 8 + j; }   // strict <: keeps first occurrence
            }
            if (v < best[i]) { best[i] = v; bidx[i] = id; }
        }
    }
    // reduce across the 16 tx-lanes (bits 0..3 of lane id, within one wave)
#pragma unroll
    for (int i = 0; i < 4; ++i) {
        float v = best[i];
        int   id = bidx[i];
#pragma unroll
        for (int o = 1; o < 16; o <<= 1) {
            float ov = __shfl_xor(v, o);
            int   oid = __shfl_xor(id, o);
            if (ov < v || (ov == v && oid < id)) { v = ov; id = oid; }
        }
        if (tx == 0) {
            pval[(size_t)cs * NTOK + m0 + ty * 4 + i] = v;
            pidx[(size_t)cs * NTOK + m0 + ty * 4 + i] = id;
        }
    }
}

// ---------------------------------------------------------------- epilogue: final argmin, gather, rotate, loss
__global__ __launch_bounds__(128) void k_epi(const float* __restrict__ x,
                                             const float* __restrict__ icb,
                                             const float* __restrict__ pval,
                                             const int*   __restrict__ pidx,
                                             float* __restrict__ out_q,
                                             float* __restrict__ out_idx,
                                             float* __restrict__ lossacc) {
    const int t = blockIdx.x;
    float v = pval[t];
    int   id = pidx[t];
#pragma unroll
    for (int s = 1; s < 4; ++s) {
        float sv = pval[(size_t)s * NTOK + t];
        int   sid = pidx[(size_t)s * NTOK + t];
        if (sv < v || (sv == v && sid < id)) { v = sv; id = sid; }
    }
    const float4* xp = (const float4*)(x   + (size_t)t * DIM);
    const float4* qp = (const float4*)(icb + (size_t)id * DIM);
    const int l = threadIdx.x;            // 0..127, one float4 each
    const float4 xv = xp[l];
    const float4 qv = qp[l];
    float p0 = xv.x * xv.x + xv.y * xv.y + xv.z * xv.z + xv.w * xv.w;
    float p1 = qv.x * qv.x + qv.y * qv.y + qv.z * qv.z + qv.w * qv.w;
    float p2 = xv.x * qv.x + xv.y * qv.y + xv.z * qv.z + xv.w * qv.w;
#pragma unroll
    for (int o = 1; o < 64; o <<= 1) {
        p0 += __shfl_xor(p0, o);
        p1 += __shfl_xor(p1, o);
        p2 += __shfl_xor(p2, o);
    }
    __shared__ float r0[2], r1[2], r2[2];
    const int w = threadIdx.x >> 6;
    if ((threadIdx.x & 63) == 0) { r0[w] = p0; r1[w] = p1; r2[w] = p2; }
    __syncthreads();
    const float sx2 = r0[0] + r0[1];
    const float sq2 = r1[0] + r1[1];
    const float sxq = r2[0] + r2[1];

    const float ns  = sqrtf(sx2);
    const float nt  = sqrtf(sq2);
    const float nsc = fmaxf(ns, EPSV);
    const float ntc = fmaxf(nt, EPSV);
    const float xu  = sx2 / nsc;                 // x . u
    const float xqh = sxq / ntc;                 // x . q_hat
    const float xw0 = xu + xqh;                  // x . (u + q_hat)
    const float w0n2 = sx2 / (nsc * nsc) + 2.f * sxq / (nsc * ntc) + sq2 / (ntc * ntc);
    const float w0nc = fmaxf(sqrtf(w0n2), EPSV);
    const float coefW = 2.f * xw0 / (w0nc * w0nc);   // multiplies w0_i = x_i/nsc + q_i/ntc
    const float coefQ = 2.f * xu / ntc;              // multiplies q_i
    const float scale = nt / nsc;
    const float cx = scale * (1.f - coefW / nsc);
    const float cq = scale * (coefQ - coefW / ntc);

    float4 ov;
    ov.x = cx * xv.x + cq * qv.x;
    ov.y = cx * xv.y + cq * qv.y;
    ov.z = cx * xv.z + cq * qv.z;
    ov.w = cx * xv.w + cq * qv.w;
    ((float4*)(out_q + (size_t)t * DIM))[l] = ov;

    if (threadIdx.x == 0) {
        out_idx[t] = (float)id;
        const float se = sx2 - 2.f * sxq + sq2;   // sum over this token of (x-q)^2
        atomicAdd(lossacc, se);
    }
}

// ---------------------------------------------------------------- launch
extern "C" void kernel_launch(void* const* d_in, const int* in_sizes, int n_in,
                              void* d_out, int out_size, void* d_ws, size_t ws_size,
                              hipStream_t stream) {
    const float* x  = (const float*)d_in[0];
    const float* cb = (const float*)d_in[1];
    const float* W1 = (const float*)d_in[2];
    const float* b1 = (const float*)d_in[3];
    const float* W2 = (const float*)d_in[4];
    const float* b2 = (const float*)d_in[5];

    char* ws = (char*)d_ws;
    float* h    = (float*)ws;                                      // 16 MB
    float* icb  = (float*)(ws + (size_t)CSIZE * DIM * 4);          // 16 MB
    float* rn2  = (float*)(ws + (size_t)2 * CSIZE * DIM * 4);      // 32 KB
    float* pval = rn2 + CSIZE;                                     // 4*NTOK floats
    int*   pidx = (int*)(pval + 4 * NTOK);                         // 4*NTOK ints
    float* lossacc = (float*)(pidx + 4 * NTOK);                    // 1 float

    float* out_q    = (float*)d_out;
    float* out_idx  = out_q + (size_t)NTOK * DIM;
    float* out_loss = out_idx + NTOK;

    k_zero<<<1, 1, 0, stream>>>(lossacc);
    k_gemm1<<<dim3(CSIZE / 64, DIM / 64), 256, 0, stream>>>(cb, W1, b1, h);
    k_gemm2<<<dim3(CSIZE / 64, DIM / 64), 256, 0, stream>>>(h, W2, b2, icb);
    k_rn2<<<CSIZE / 4, 256, 0, stream>>>(icb, rn2);
    k_dist<<<dim3(NTOK / 64, 4), 256, 0, stream>>>(x, icb, rn2, pval, pidx);
    k_epi<<<NTOK, 128, 0, stream>>>(x, icb, pval, pidx, out_q, out_idx, lossacc);
    k_fin<<<1, 1, 0, stream>>>(lossacc, out_loss);
}

// Round 3
// 824.072 us; speedup vs baseline: 4.7928x; 4.7928x over previous
//
#include <hip/hip_runtime.h>
#include <math.h>

#define DIM   512
#define CDIM  128
#define CSIZE 8192
#define NTOK  16384          // 4 * 4096
#define EPSV  1e-6f
#define NSLICE 4             // code slices for k_dist grid.y
#define NSLICE2 (2 * NSLICE) // effective slices: each wave column-half writes its own

#define SELU_SCALE 1.0507009873554805f
#define SELU_ALPHA 1.6732632423543772f

typedef __bf16 bf16x8 __attribute__((ext_vector_type(8)));
typedef float  f32x4  __attribute__((ext_vector_type(4)));

__device__ __forceinline__ float selu_f(float v) {
    return SELU_SCALE * (v > 0.f ? v : SELU_ALPHA * expm1f(v));
}

// RNE float -> bf16 bits
__device__ __forceinline__ unsigned short b16(float f) {
    unsigned u = __float_as_uint(f);
    u += 0x7FFFu + ((u >> 16) & 1u);
    return (unsigned short)(u >> 16);
}
__device__ __forceinline__ float b2f(unsigned short h) {
    return __uint_as_float(((unsigned)h) << 16);
}

#define GLOAD16(g, l) __builtin_amdgcn_global_load_lds( \
    (const __attribute__((address_space(1))) void*)(g),  \
    (__attribute__((address_space(3))) void*)(l), 16, 0, 0)

// ---------------------------------------------------------------- zero / fin
__global__ void k_zero(float* __restrict__ acc) { acc[0] = 0.f; }

__global__ void k_fin(const float* __restrict__ acc, float* __restrict__ out_loss) {
    out_loss[0] = 1.25f * acc[0] / (float)((size_t)NTOK * DIM);
}

// ---------------------------------------------------------------- split f32 -> bf16 hi/lo
__global__ __launch_bounds__(256) void k_split(const float* __restrict__ in,
                                               unsigned short* __restrict__ hi,
                                               unsigned short* __restrict__ lo,
                                               int n4) {
    const int i = blockIdx.x * 256 + threadIdx.x;
    if (i >= n4) return;
    const float4 v = ((const float4*)in)[i];
    const unsigned short h0 = b16(v.x), h1 = b16(v.y), h2 = b16(v.z), h3 = b16(v.w);
    const unsigned short l0 = b16(v.x - b2f(h0));
    const unsigned short l1 = b16(v.y - b2f(h1));
    const unsigned short l2 = b16(v.z - b2f(h2));
    const unsigned short l3 = b16(v.w - b2f(h3));
    ((ushort4*)hi)[i] = make_ushort4(h0, h1, h2, h3);
    ((ushort4*)lo)[i] = make_ushort4(l0, l1, l2, l3);
}

// ---------------------------------------------------------------- GEMM1: h = cb@W1 + b1  (f32, small)
__global__ __launch_bounds__(256) void k_gemm1(const float* __restrict__ cb,
                                               const float* __restrict__ W1,
                                               const float* __restrict__ b1,
                                               float* __restrict__ h) {
    __shared__ float a_t[32][68];
    __shared__ float b_t[32][68];
    const int m0 = blockIdx.x * 64;
    const int n0 = blockIdx.y * 64;
    const int tid = threadIdx.x;
    const int tx = tid & 15, ty = tid >> 4;
    float acc[4][4] = {};
    for (int k0 = 0; k0 < CDIM; k0 += 32) {
        for (int l = tid; l < 64 * 32; l += 256) {
            int m = l >> 5, kk = l & 31;
            a_t[kk][m] = cb[(size_t)(m0 + m) * CDIM + k0 + kk];
        }
        for (int l = tid; l < 32 * 64; l += 256) {
            int kk = l >> 6, nn = l & 63;
            b_t[kk][nn] = W1[(size_t)(k0 + kk) * DIM + n0 + nn];
        }
        __syncthreads();
#pragma unroll
        for (int kk = 0; kk < 32; ++kk) {
            const float4 av = *(const float4*)&a_t[kk][ty * 4];
            const float4 bv = *(const float4*)&b_t[kk][tx * 4];
            float a[4] = {av.x, av.y, av.z, av.w};
            float b[4] = {bv.x, bv.y, bv.z, bv.w};
#pragma unroll
            for (int i = 0; i < 4; ++i)
#pragma unroll
                for (int j = 0; j < 4; ++j)
                    acc[i][j] = fmaf(a[i], b[j], acc[i][j]);
        }
        __syncthreads();
    }
#pragma unroll
    for (int i = 0; i < 4; ++i) {
        const int m = m0 + ty * 4 + i;
#pragma unroll
        for (int j = 0; j < 4; ++j) {
            const int n = n0 + tx * 4 + j;
            h[(size_t)m * DIM + n] = acc[i][j] + b1[n];
        }
    }
}

// ---------------------------------------------------------------- GEMM2: icb = h + selu(h)@W2 + b2
__global__ __launch_bounds__(256) void k_gemm2(const float* __restrict__ h,
                                               const float* __restrict__ W2,
                                               const float* __restrict__ b2,
                                               float* __restrict__ icb) {
    __shared__ float a_t[32][68];
    __shared__ float b_t[32][68];
    const int m0 = blockIdx.x * 64;
    const int n0 = blockIdx.y * 64;
    const int tid = threadIdx.x;
    const int tx = tid & 15, ty = tid >> 4;
    float acc[4][4] = {};
    for (int k0 = 0; k0 < DIM; k0 += 32) {
        for (int l = tid; l < 64 * 32; l += 256) {
            int m = l >> 5, kk = l & 31;
            a_t[kk][m] = selu_f(h[(size_t)(m0 + m) * DIM + k0 + kk]);
        }
        for (int l = tid; l < 32 * 64; l += 256) {
            int kk = l >> 6, nn = l & 63;
            b_t[kk][nn] = W2[(size_t)(k0 + kk) * DIM + n0 + nn];
        }
        __syncthreads();
#pragma unroll
        for (int kk = 0; kk < 32; ++kk) {
            const float4 av = *(const float4*)&a_t[kk][ty * 4];
            const float4 bv = *(const float4*)&b_t[kk][tx * 4];
            float a[4] = {av.x, av.y, av.z, av.w};
            float b[4] = {bv.x, bv.y, bv.z, bv.w};
#pragma unroll
            for (int i = 0; i < 4; ++i)
#pragma unroll
                for (int j = 0; j < 4; ++j)
                    acc[i][j] = fmaf(a[i], b[j], acc[i][j]);
        }
        __syncthreads();
    }
#pragma unroll
    for (int i = 0; i < 4; ++i) {
        const int m = m0 + ty * 4 + i;
#pragma unroll
        for (int j = 0; j < 4; ++j) {
            const int n = n0 + tx * 4 + j;
            icb[(size_t)m * DIM + n] = acc[i][j] + h[(size_t)m * DIM + n] + b2[n];
        }
    }
}

// ---------------------------------------------------------------- code norms
__global__ __launch_bounds__(256) void k_rn2(const float* __restrict__ icb,
                                             float* __restrict__ rn2) {
    const int row  = blockIdx.x * 4 + (threadIdx.x >> 6);
    const int lane = threadIdx.x & 63;
    const float4* p = (const float4*)(icb + (size_t)row * DIM);
    float s = 0.f;
#pragma unroll
    for (int it = 0; it < DIM / 4 / 64; ++it) {
        float4 v = p[lane + 64 * it];
        s += v.x * v.x + v.y * v.y + v.z * v.z + v.w * v.w;
    }
#pragma unroll
    for (int o = 32; o > 0; o >>= 1) s += __shfl_xor(s, o);
    if (lane == 0) rn2[row] = s;
}

// ---------------------------------------------------------------- MFMA distance + partial argmin
// Block: 128 tokens x 2048 codes (16 n-tiles of 128). 4 waves, each 64x64.
// Wave (wm0, wn0) covers token rows [wm0,wm0+64) and code cols [wn0,wn0+64) of
// the tile. Each wave's column half is its OWN output slice
// (slice = blockIdx.y*2 + (wave&1)) so no two waves share a pval/pidx slot.
// d2' = rn2[c] - 2*(xh.ch + xh.cl + xl.ch) via mfma_f32_16x16x32_bf16.
// LDS: 4 tiles [128 rows][32 bf16] = 4*8KB, linear gload_lds dest,
// swizzle involution SWZ(b) = b ^ (((b>>6)&14)<<3) applied to global source
// and ds_read addresses (<=2-way bank aliasing = free).
__global__ __launch_bounds__(256, 2) void k_dist(const unsigned short* __restrict__ xh,
                                                 const unsigned short* __restrict__ xl,
                                                 const unsigned short* __restrict__ ch,
                                                 const unsigned short* __restrict__ cl,
                                                 const float* __restrict__ rn2,
                                                 float* __restrict__ pval,
                                                 int*   __restrict__ pidx) {
    __shared__ __align__(16) unsigned char smem[32768];   // AH|AL|BH|BL, 8192B each
    const int tid  = threadIdx.x;
    const int wave = tid >> 6, lane = tid & 63;
    const int m0   = blockIdx.x * 128;
    const int wm0  = (wave >> 1) * 64;     // wave row offset in tile
    const int wn0  = (wave & 1) * 64;      // wave col offset in tile

    // staging: chunk c -> LDS byte p=16c (linear); source row/col from L = SWZ(p)
    int soff[2];
#pragma unroll
    for (int rnd = 0; rnd < 2; ++rnd) {
        const int p = (tid + rnd * 256) * 16;
        const int L = p ^ (((p >> 6) & 14) << 3);
        soff[rnd] = (L >> 6) * DIM + ((L >> 4) & 3) * 8;  // ushort elems within tile
    }
    const unsigned ldsoff0 = (unsigned)wave * 1024u;          // wave-uniform dest base, round 0
    const unsigned ldsoff1 = 4096u + (unsigned)wave * 1024u;  // round 1

    // fragment ds_read addresses (within-tile bytes, swizzled; k0-independent)
    unsigned ra[4], rb[4];
#pragma unroll
    for (int f = 0; f < 4; ++f) {
        const int bA = (wm0 + f * 16 + (lane & 15)) * 64 + (lane >> 4) * 16;
        ra[f] = (unsigned)(bA ^ (((bA >> 6) & 14) << 3));
        const int bB = (wn0 + f * 16 + (lane & 15)) * 64 + (lane >> 4) * 16;
        rb[f] = (unsigned)(bB ^ (((bB >> 6) & 14) << 3));
    }

    float bestv[4][4];
    int   besti[4][4];
#pragma unroll
    for (int a = 0; a < 4; ++a)
#pragma unroll
        for (int b = 0; b < 4; ++b) { bestv[a][b] = 3.0e38f; besti[a][b] = 0; }

    const unsigned short* xhb = xh + (size_t)m0 * DIM;
    const unsigned short* xlb = xl + (size_t)m0 * DIM;

    for (int nt = 0; nt < (CSIZE / NSLICE) / 128; ++nt) {
        const int n0 = blockIdx.y * (CSIZE / NSLICE) + nt * 128;
        const unsigned short* chb = ch + (size_t)n0 * DIM;
        const unsigned short* clb = cl + (size_t)n0 * DIM;

        f32x4 acc[4][4];
#pragma unroll
        for (int a = 0; a < 4; ++a)
#pragma unroll
            for (int b = 0; b < 4; ++b) acc[a][b] = (f32x4)(0.f);

        for (int k0 = 0; k0 < DIM; k0 += 32) {
            __syncthreads();   // previous tiles fully consumed
            {
                const int s0 = soff[0] + k0;
                GLOAD16(xhb + s0, smem + 0     + ldsoff0);
                GLOAD16(xlb + s0, smem + 8192  + ldsoff0);
                GLOAD16(chb + s0, smem + 16384 + ldsoff0);
                GLOAD16(clb + s0, smem + 24576 + ldsoff0);
                const int s1 = soff[1] + k0;
                GLOAD16(xhb + s1, smem + 0     + ldsoff1);
                GLOAD16(xlb + s1, smem + 8192  + ldsoff1);
                GLOAD16(chb + s1, smem + 16384 + ldsoff1);
                GLOAD16(clb + s1, smem + 24576 + ldsoff1);
            }
            __syncthreads();   // compiler drains vmcnt before s_barrier: tiles ready

            bf16x8 ah[4], al[4], bh[4], bl[4];
#pragma unroll
            for (int f = 0; f < 4; ++f) {
                ah[f] = *(const bf16x8*)(smem + ra[f]);
                al[f] = *(const bf16x8*)(smem + 8192 + ra[f]);
                bh[f] = *(const bf16x8*)(smem + 16384 + rb[f]);
                bl[f] = *(const bf16x8*)(smem + 24576 + rb[f]);
            }
#pragma unroll
            for (int mi = 0; mi < 4; ++mi)
#pragma unroll
                for (int ni = 0; ni < 4; ++ni) {
                    acc[mi][ni] = __builtin_amdgcn_mfma_f32_16x16x32_bf16(ah[mi], bh[ni], acc[mi][ni], 0, 0, 0);
                    acc[mi][ni] = __builtin_amdgcn_mfma_f32_16x16x32_bf16(ah[mi], bl[ni], acc[mi][ni], 0, 0, 0);
                    acc[mi][ni] = __builtin_amdgcn_mfma_f32_16x16x32_bf16(al[mi], bh[ni], acc[mi][ni], 0, 0, 0);
                }
        }

        // fold this n-tile into per-lane running best.
        // C layout (16x16x32): col = lane&15, row = (lane>>4)*4 + reg
        const int tcol = lane & 15;
#pragma unroll
        for (int ni = 0; ni < 4; ++ni) {
            const int n = n0 + wn0 + ni * 16 + tcol;
            const float r = rn2[n];
#pragma unroll
            for (int mi = 0; mi < 4; ++mi)
#pragma unroll
                for (int rr = 0; rr < 4; ++rr) {
                    const float v = fmaf(-2.f, acc[mi][ni][rr], r);
                    if (v < bestv[mi][rr]) { bestv[mi][rr] = v; besti[mi][rr] = n; }
                }
        }
    }

    // cross-lane reduce over the 16 column-lanes (xor bits 0..3), write partials.
    // Each wave writes its own slice: no cross-wave sharing of (slice, m) slots.
    const int slice = blockIdx.y * 2 + (wave & 1);
#pragma unroll
    for (int mi = 0; mi < 4; ++mi)
#pragma unroll
        for (int rr = 0; rr < 4; ++rr) {
            float v = bestv[mi][rr];
            int   id = besti[mi][rr];
#pragma unroll
            for (int o = 1; o < 16; o <<= 1) {
                const float ov = __shfl_xor(v, o);
                const int   oid = __shfl_xor(id, o);
                if (ov < v || (ov == v && oid < id)) { v = ov; id = oid; }
            }
            if ((lane & 15) == 0) {
                const int m = m0 + wm0 + mi * 16 + (lane >> 4) * 4 + rr;
                pval[(size_t)slice * NTOK + m] = v;
                pidx[(size_t)slice * NTOK + m] = id;
            }
        }
}

// ---------------------------------------------------------------- epilogue: final argmin, gather, rotate, loss
__global__ __launch_bounds__(128) void k_epi(const float* __restrict__ x,
                                             const float* __restrict__ icb,
                                             const float* __restrict__ pval,
                                             const int*   __restrict__ pidx,
                                             float* __restrict__ out_q,
                                             float* __restrict__ out_idx,
                                             float* __restrict__ lossacc) {
    const int t = blockIdx.x;
    float v = pval[t];
    int   id = pidx[t];
#pragma unroll
    for (int s = 1; s < NSLICE2; ++s) {
        const float sv = pval[(size_t)s * NTOK + t];
        const int   sid = pidx[(size_t)s * NTOK + t];
        if (sv < v || (sv == v && sid < id)) { v = sv; id = sid; }
    }
    const float4* xp = (const float4*)(x   + (size_t)t * DIM);
    const float4* qp = (const float4*)(icb + (size_t)id * DIM);
    const int l = threadIdx.x;
    const float4 xv = xp[l];
    const float4 qv = qp[l];
    float p0 = xv.x * xv.x + xv.y * xv.y + xv.z * xv.z + xv.w * xv.w;
    float p1 = qv.x * qv.x + qv.y * qv.y + qv.z * qv.z + qv.w * qv.w;
    float p2 = xv.x * qv.x + xv.y * qv.y + xv.z * qv.z + xv.w * qv.w;
#pragma unroll
    for (int o = 1; o < 64; o <<= 1) {
        p0 += __shfl_xor(p0, o);
        p1 += __shfl_xor(p1, o);
        p2 += __shfl_xor(p2, o);
    }
    __shared__ float r0[2], r1[2], r2[2];
    const int w = threadIdx.x >> 6;
    if ((threadIdx.x & 63) == 0) { r0[w] = p0; r1[w] = p1; r2[w] = p2; }
    __syncthreads();
    const float sx2 = r0[0] + r0[1];
    const float sq2 = r1[0] + r1[1];
    const float sxq = r2[0] + r2[1];

    const float ns  = sqrtf(sx2);
    const float nt  = sqrtf(sq2);
    const float nsc = fmaxf(ns, EPSV);
    const float ntc = fmaxf(nt, EPSV);
    const float xu  = sx2 / nsc;
    const float xqh = sxq / ntc;
    const float xw0 = xu + xqh;
    const float w0n2 = sx2 / (nsc * nsc) + 2.f * sxq / (nsc * ntc) + sq2 / (ntc * ntc);
    const float w0nc = fmaxf(sqrtf(w0n2), EPSV);
    const float coefW = 2.f * xw0 / (w0nc * w0nc);
    const float coefQ = 2.f * xu / ntc;
    const float scale = nt / nsc;
    const float cx = scale * (1.f - coefW / nsc);
    const float cq = scale * (coefQ - coefW / ntc);

    float4 ov;
    ov.x = cx * xv.x + cq * qv.x;
    ov.y = cx * xv.y + cq * qv.y;
    ov.z = cx * xv.z + cq * qv.z;
    ov.w = cx * xv.w + cq * qv.w;
    ((float4*)(out_q + (size_t)t * DIM))[l] = ov;

    if (threadIdx.x == 0) {
        out_idx[t] = (float)id;
        const float se = sx2 - 2.f * sxq + sq2;
        atomicAdd(lossacc, se);
    }
}

// ---------------------------------------------------------------- launch
extern "C" void kernel_launch(void* const* d_in, const int* in_sizes, int n_in,
                              void* d_out, int out_size, void* d_ws, size_t ws_size,
                              hipStream_t stream) {
    const float* x  = (const float*)d_in[0];
    const float* cb = (const float*)d_in[1];
    const float* W1 = (const float*)d_in[2];
    const float* b1 = (const float*)d_in[3];
    const float* W2 = (const float*)d_in[4];
    const float* b2 = (const float*)d_in[5];

    char* ws = (char*)d_ws;
    float* h    = (float*)ws;                                  // 16.78 MB
    float* icb  = h + (size_t)CSIZE * DIM;                     // 16.78 MB
    float* rn2  = icb + (size_t)CSIZE * DIM;                   // 32 KB
    float* pval = rn2 + CSIZE;                                 // 8*NTOK f32
    int*   pidx = (int*)(pval + (size_t)NSLICE2 * NTOK);       // 8*NTOK i32
    float* lossacc = (float*)(pidx + (size_t)NSLICE2 * NTOK);

    // code splits overlay h (h is dead after k_gemm2)
    unsigned short* chi = (unsigned short*)h;
    unsigned short* clo = chi + (size_t)CSIZE * DIM;

    // x splits overlay d_out's out_q region (dead until k_epi writes it)
    unsigned short* xhi = (unsigned short*)d_out;
    unsigned short* xlo = xhi + (size_t)NTOK * DIM;

    float* out_q    = (float*)d_out;
    float* out_idx  = out_q + (size_t)NTOK * DIM;
    float* out_loss = out_idx + NTOK;

    k_zero<<<1, 1, 0, stream>>>(lossacc);
    k_split<<<(NTOK * DIM / 4) / 256, 256, 0, stream>>>(x, xhi, xlo, NTOK * DIM / 4);
    k_gemm1<<<dim3(CSIZE / 64, DIM / 64), 256, 0, stream>>>(cb, W1, b1, h);
    k_gemm2<<<dim3(CSIZE / 64, DIM / 64), 256, 0, stream>>>(h, W2, b2, icb);
    k_split<<<(CSIZE * DIM / 4) / 256, 256, 0, stream>>>(icb, chi, clo, CSIZE * DIM / 4);
    k_rn2<<<CSIZE / 4, 256, 0, stream>>>(icb, rn2);
    k_dist<<<dim3(NTOK / 128, NSLICE), 256, 0, stream>>>(xhi, xlo, chi, clo, rn2, pval, pidx);
    k_epi<<<NTOK, 128, 0, stream>>>(x, icb, pval, pidx, out_q, out_idx, lossacc);
    k_fin<<<1, 1, 0, stream>>>(lossacc, out_loss);
}

// Round 4
// 710.203 us; speedup vs baseline: 5.5612x; 1.1603x over previous
//
#include <hip/hip_runtime.h>
#include <math.h>

#define DIM   512
#define CDIM  128
#define CSIZE 8192
#define NTOK  16384          // 4 * 4096
#define EPSV  1e-6f
#define NSLICE 8             // k_dist grid.y code slices
#define NSLICE2 (2 * NSLICE) // each wave column-half writes its own slice

#define SELU_SCALE 1.0507009873554805f
#define SELU_ALPHA 1.6732632423543772f

typedef __bf16 bf16x8 __attribute__((ext_vector_type(8)));
typedef float  f32x4  __attribute__((ext_vector_type(4)));
typedef unsigned short u16x8 __attribute__((ext_vector_type(8)));

__device__ __forceinline__ float selu_f(float v) {
    return SELU_SCALE * (v > 0.f ? v : SELU_ALPHA * expm1f(v));
}

// RNE float -> bf16 bits
__device__ __forceinline__ unsigned short b16(float f) {
    unsigned u = __float_as_uint(f);
    u += 0x7FFFu + ((u >> 16) & 1u);
    return (unsigned short)(u >> 16);
}
__device__ __forceinline__ float b2f(unsigned short h) {
    return __uint_as_float(((unsigned)h) << 16);
}

// LDS byte-swizzle involution (verified 0 bank conflicts in round 3)
__device__ __forceinline__ unsigned SWZ(unsigned b) {
    return b ^ (((b >> 6) & 14u) << 3);
}

#define GLOAD16(g, l) __builtin_amdgcn_global_load_lds( \
    (const __attribute__((address_space(1))) void*)(g),  \
    (__attribute__((address_space(3))) void*)(l), 16, 0, 0)

// ---------------------------------------------------------------- zero / fin
__global__ void k_zero(float* __restrict__ acc) { acc[0] = 0.f; }

__global__ void k_fin(const float* __restrict__ acc, float* __restrict__ out_loss) {
    out_loss[0] = 1.25f * acc[0] / (float)((size_t)NTOK * DIM);
}

// ---------------------------------------------------------------- split f32 -> bf16 hi/lo (row-major passthrough)
__global__ __launch_bounds__(256) void k_split(const float* __restrict__ in,
                                               unsigned short* __restrict__ hi,
                                               unsigned short* __restrict__ lo,
                                               int n4) {
    const int i = blockIdx.x * 256 + threadIdx.x;
    if (i >= n4) return;
    const float4 v = ((const float4*)in)[i];
    const unsigned short h0 = b16(v.x), h1 = b16(v.y), h2 = b16(v.z), h3 = b16(v.w);
    const unsigned short l0 = b16(v.x - b2f(h0));
    const unsigned short l1 = b16(v.y - b2f(h1));
    const unsigned short l2 = b16(v.z - b2f(h2));
    const unsigned short l3 = b16(v.w - b2f(h3));
    ((ushort4*)hi)[i] = make_ushort4(h0, h1, h2, h3);
    ((ushort4*)lo)[i] = make_ushort4(l0, l1, l2, l3);
}

// ---------------------------------------------------------------- transpose + split: W[K,N] -> WT hi/lo [N,K]
__global__ __launch_bounds__(256) void k_splitT(const float* __restrict__ W,
                                                unsigned short* __restrict__ Thi,
                                                unsigned short* __restrict__ Tlo,
                                                int K, int N) {
    __shared__ float t[32][33];
    const int tx = threadIdx.x & 31, ty = threadIdx.x >> 5;   // 32 x 8
    const int n0 = blockIdx.x * 32, k0 = blockIdx.y * 32;
#pragma unroll
    for (int i = 0; i < 4; ++i)
        t[ty + i * 8][tx] = W[(size_t)(k0 + ty + i * 8) * N + n0 + tx];
    __syncthreads();
#pragma unroll
    for (int i = 0; i < 4; ++i) {
        const int n = n0 + ty + i * 8, k = k0 + tx;
        const float v = t[tx][ty + i * 8];
        const unsigned short h = b16(v);
        Thi[(size_t)n * K + k] = h;
        Tlo[(size_t)n * K + k] = b16(v - b2f(h));
    }
}

// ---------------------------------------------------------------- MFMA GEMM (split-bf16, 3-term)
// out[m][n] = sum_k A'[m][k]*W[k][n] + bias[n] (+ res[m][n])
// A' = SELU_RES ? selu(A) : A.  BT hi/lo = W transposed+split [N, KTOT].
// Block 128x128, 4 waves of 64x64. A reg-staged (f32 -> selu -> split -> swizzled
// ds_write); B via gload_lds (linear dest + SWZ'd source). Reads SWZ'd (both-sides rule).
template<int KTOT, bool SELU_RES>
__global__ __launch_bounds__(256) void k_gemm(const float* __restrict__ A,
                                              const unsigned short* __restrict__ BThi,
                                              const unsigned short* __restrict__ BTlo,
                                              const float* __restrict__ bias,
                                              const float* __restrict__ res,
                                              float* __restrict__ out) {
    __shared__ __align__(16) unsigned char smem[32768];   // AH|AL|BH|BL, 8KB each
    const int tid = threadIdx.x;
    const int wave = tid >> 6, lane = tid & 63;
    const int l15 = lane & 15, l4 = lane >> 4;
    const int m0 = blockIdx.x * 128, n0 = blockIdx.y * 128;
    const int wm0 = (wave >> 1) * 64, wn0 = (wave & 1) * 64;

    // B staging source offset (round 0); rounds add r*64*KTOT (mask is r-independent)
    const unsigned pB = (unsigned)tid * 16u;
    const unsigned LB = SWZ(pB);
    const int soffB0 = (int)(LB >> 6) * KTOT + (int)((LB >> 4) & 3) * 8;

    // fragment read offsets (round-3-verified formulas; mi/ni strides are +1024)
    const unsigned ra0 = SWZ((unsigned)((wm0 + l15) * 64 + l4 * 16));
    const unsigned rb0 = SWZ((unsigned)((wn0 + l15) * 64 + l4 * 16));

    f32x4 acc[4][4];
#pragma unroll
    for (int a = 0; a < 4; ++a)
#pragma unroll
        for (int b = 0; b < 4; ++b) acc[a][b] = (f32x4)(0.f);

    for (int k0 = 0; k0 < KTOT; k0 += 32) {
        __syncthreads();
        // B: global_load_lds, linear dest
#pragma unroll
        for (int r = 0; r < 2; ++r) {
            GLOAD16(BThi + (size_t)n0 * KTOT + k0 + soffB0 + r * 64 * KTOT,
                    smem + 16384 + r * 4096 + wave * 1024);
            GLOAD16(BTlo + (size_t)n0 * KTOT + k0 + soffB0 + r * 64 * KTOT,
                    smem + 24576 + r * 4096 + wave * 1024);
        }
        // A: reg-stage f32 -> (selu) -> split -> ds_write at SWZ(linear)
#pragma unroll
        for (int r = 0; r < 2; ++r) {
            const unsigned g = (unsigned)(tid + r * 256) * 16u;   // linear byte in [128][64B]
            const int grow = (int)(g >> 6), gel = (int)((g >> 4) & 3) * 8;
            const float4 v0 = *(const float4*)(A + (size_t)(m0 + grow) * KTOT + k0 + gel);
            const float4 v1 = *(const float4*)(A + (size_t)(m0 + grow) * KTOT + k0 + gel + 4);
            float s[8] = {v0.x, v0.y, v0.z, v0.w, v1.x, v1.y, v1.z, v1.w};
            u16x8 hv, lv;
#pragma unroll
            for (int j = 0; j < 8; ++j) {
                const float sv = SELU_RES ? selu_f(s[j]) : s[j];
                const unsigned short hb = b16(sv);
                hv[j] = hb;
                lv[j] = b16(sv - b2f(hb));
            }
            const unsigned d = SWZ(g);
            *(u16x8*)(smem + d) = hv;
            *(u16x8*)(smem + 8192 + d) = lv;
        }
        __syncthreads();

        bf16x8 bh[4], bl[4];
#pragma unroll
        for (int ni = 0; ni < 4; ++ni) {
            bh[ni] = *(const bf16x8*)(smem + 16384 + rb0 + ni * 1024);
            bl[ni] = *(const bf16x8*)(smem + 24576 + rb0 + ni * 1024);
        }
#pragma unroll
        for (int mi = 0; mi < 4; ++mi) {
            const bf16x8 ah = *(const bf16x8*)(smem + ra0 + mi * 1024);
            const bf16x8 al = *(const bf16x8*)(smem + 8192 + ra0 + mi * 1024);
#pragma unroll
            for (int ni = 0; ni < 4; ++ni) {
                acc[mi][ni] = __builtin_amdgcn_mfma_f32_16x16x32_bf16(ah, bh[ni], acc[mi][ni], 0, 0, 0);
                acc[mi][ni] = __builtin_amdgcn_mfma_f32_16x16x32_bf16(ah, bl[ni], acc[mi][ni], 0, 0, 0);
                acc[mi][ni] = __builtin_amdgcn_mfma_f32_16x16x32_bf16(al, bh[ni], acc[mi][ni], 0, 0, 0);
            }
        }
    }
    // epilogue: C layout col = lane&15, row = (lane>>4)*4 + reg
#pragma unroll
    for (int mi = 0; mi < 4; ++mi)
#pragma unroll
        for (int rr = 0; rr < 4; ++rr) {
            const int m = m0 + wm0 + mi * 16 + l4 * 4 + rr;
#pragma unroll
            for (int ni = 0; ni < 4; ++ni) {
                const int n = n0 + wn0 + ni * 16 + l15;
                float v = acc[mi][ni][rr] + bias[n];
                if (SELU_RES) v += res[(size_t)m * DIM + n];
                out[(size_t)m * DIM + n] = v;
            }
        }
}

// ---------------------------------------------------------------- code norms
__global__ __launch_bounds__(256) void k_rn2(const float* __restrict__ icb,
                                             float* __restrict__ rn2) {
    const int row  = blockIdx.x * 4 + (threadIdx.x >> 6);
    const int lane = threadIdx.x & 63;
    const float4* p = (const float4*)(icb + (size_t)row * DIM);
    float s = 0.f;
#pragma unroll
    for (int it = 0; it < DIM / 4 / 64; ++it) {
        float4 v = p[lane + 64 * it];
        s += v.x * v.x + v.y * v.y + v.z * v.z + v.w * v.w;
    }
#pragma unroll
    for (int o = 32; o > 0; o >>= 1) s += __shfl_xor(s, o);
    if (lane == 0) rn2[row] = s;
}

// ---------------------------------------------------------------- MFMA distance + partial argmin
// Block: 256 tokens x 1024 codes (8 n-tiles of 128). 4 waves (2x2), each 128x64
// (halves LDS bytes/FLOP vs 64x64 -> lifts the LDS-read-BW bound).
// Wave col-half writes its own slice (slice = blockIdx.y*2 + (wave&1)) - no races.
// d2' = rn2[c] - 2*(xh.ch + xh.cl + xl.ch), mfma_f32_16x16x32_bf16.
// LDS 48KB: AH[256][32]@0 16K, AL@16384 16K, BH[128][32]@32768 8K, BL@40960 8K.
// Linear gload_lds dest + SWZ'd global source + SWZ'd ds_read (both-sides rule).
__global__ __launch_bounds__(256, 2) void k_dist(const unsigned short* __restrict__ xh,
                                                 const unsigned short* __restrict__ xl,
                                                 const unsigned short* __restrict__ ch,
                                                 const unsigned short* __restrict__ cl,
                                                 const float* __restrict__ rn2,
                                                 float* __restrict__ pval,
                                                 int*   __restrict__ pidx) {
    __shared__ __align__(16) unsigned char smem[49152];
    const int tid  = threadIdx.x;
    const int wave = tid >> 6, lane = tid & 63;
    const int l15 = lane & 15, l4 = lane >> 4;
    const int m0   = blockIdx.x * 256;
    const int wm0  = (wave >> 1) * 128;    // wave row offset in tile
    const int wn0  = (wave & 1) * 64;      // wave col offset in tile

    // staging source offset (round 0); round r adds r*64*DIM (SWZ mask r-independent)
    const unsigned pS = (unsigned)tid * 16u;
    const unsigned LS = SWZ(pS);
    const int soff0 = (int)(LS >> 6) * DIM + (int)((LS >> 4) & 3) * 8;

    // fragment read offsets; mi/ni strides are +1024 bytes (mask mi-independent)
    const unsigned ra0 = SWZ((unsigned)((wm0 + l15) * 64 + l4 * 16));
    const unsigned rb0 = SWZ((unsigned)((wn0 + l15) * 64 + l4 * 16));

    float bestv[8][4];
    int   besti[8][4];
#pragma unroll
    for (int a = 0; a < 8; ++a)
#pragma unroll
        for (int b = 0; b < 4; ++b) { bestv[a][b] = 3.0e38f; besti[a][b] = 0; }

    const unsigned short* xhb = xh + (size_t)m0 * DIM;
    const unsigned short* xlb = xl + (size_t)m0 * DIM;
    const int cbase = blockIdx.y * (CSIZE / NSLICE);

    for (int nt = 0; nt < (CSIZE / NSLICE) / 128; ++nt) {
        const int n0 = cbase + nt * 128;
        const unsigned short* chb = ch + (size_t)n0 * DIM;
        const unsigned short* clb = cl + (size_t)n0 * DIM;

        f32x4 acc[8][4];
#pragma unroll
        for (int a = 0; a < 8; ++a)
#pragma unroll
            for (int b = 0; b < 4; ++b) acc[a][b] = (f32x4)(0.f);

        for (int k0 = 0; k0 < DIM; k0 += 32) {
            __syncthreads();   // previous tiles fully consumed
            const int sA = soff0 + k0;
#pragma unroll
            for (int r = 0; r < 4; ++r) {
                GLOAD16(xhb + sA + r * 64 * DIM, smem + 0     + r * 4096 + wave * 1024);
                GLOAD16(xlb + sA + r * 64 * DIM, smem + 16384 + r * 4096 + wave * 1024);
            }
#pragma unroll
            for (int r = 0; r < 2; ++r) {
                GLOAD16(chb + sA + r * 64 * DIM, smem + 32768 + r * 4096 + wave * 1024);
                GLOAD16(clb + sA + r * 64 * DIM, smem + 40960 + r * 4096 + wave * 1024);
            }
            __syncthreads();   // vmcnt drained before barrier: tiles ready

            bf16x8 bh[4], bl[4];
#pragma unroll
            for (int ni = 0; ni < 4; ++ni) {
                bh[ni] = *(const bf16x8*)(smem + 32768 + rb0 + ni * 1024);
                bl[ni] = *(const bf16x8*)(smem + 40960 + rb0 + ni * 1024);
            }
#pragma unroll
            for (int mi = 0; mi < 8; ++mi) {
                const bf16x8 ah = *(const bf16x8*)(smem + ra0 + mi * 1024);
                const bf16x8 al = *(const bf16x8*)(smem + 16384 + ra0 + mi * 1024);
#pragma unroll
                for (int ni = 0; ni < 4; ++ni) {
                    acc[mi][ni] = __builtin_amdgcn_mfma_f32_16x16x32_bf16(ah, bh[ni], acc[mi][ni], 0, 0, 0);
                    acc[mi][ni] = __builtin_amdgcn_mfma_f32_16x16x32_bf16(ah, bl[ni], acc[mi][ni], 0, 0, 0);
                    acc[mi][ni] = __builtin_amdgcn_mfma_f32_16x16x32_bf16(al, bh[ni], acc[mi][ni], 0, 0, 0);
                }
            }
        }

        // fold this n-tile into per-lane running best (d2 minus per-token ||x||^2)
#pragma unroll
        for (int ni = 0; ni < 4; ++ni) {
            const int n = n0 + wn0 + ni * 16 + l15;
            const float r = rn2[n];
#pragma unroll
            for (int mi = 0; mi < 8; ++mi)
#pragma unroll
                for (int rr = 0; rr < 4; ++rr) {
                    const float v = fmaf(-2.f, acc[mi][ni][rr], r);
                    if (v < bestv[mi][rr]) { bestv[mi][rr] = v; besti[mi][rr] = n; }
                }
        }
    }

    // reduce across the 16 column-lanes (xor bits 0..3); each wave owns its slice
    const int slice = blockIdx.y * 2 + (wave & 1);
#pragma unroll
    for (int mi = 0; mi < 8; ++mi)
#pragma unroll
        for (int rr = 0; rr < 4; ++rr) {
            float v = bestv[mi][rr];
            int   id = besti[mi][rr];
#pragma unroll
            for (int o = 1; o < 16; o <<= 1) {
                const float ov = __shfl_xor(v, o);
                const int   oid = __shfl_xor(id, o);
                if (ov < v || (ov == v && oid < id)) { v = ov; id = oid; }
            }
            if (l15 == 0) {
                const int m = m0 + wm0 + mi * 16 + l4 * 4 + rr;
                pval[(size_t)slice * NTOK + m] = v;
                pidx[(size_t)slice * NTOK + m] = id;
            }
        }
}

// ---------------------------------------------------------------- epilogue: final argmin, gather, rotate, loss
__global__ __launch_bounds__(128) void k_epi(const float* __restrict__ x,
                                             const float* __restrict__ icb,
                                             const float* __restrict__ pval,
                                             const int*   __restrict__ pidx,
                                             float* __restrict__ out_q,
                                             float* __restrict__ out_idx,
                                             float* __restrict__ lossacc) {
    const int t = blockIdx.x;
    float v = pval[t];
    int   id = pidx[t];
#pragma unroll
    for (int s = 1; s < NSLICE2; ++s) {
        const float sv = pval[(size_t)s * NTOK + t];
        const int   sid = pidx[(size_t)s * NTOK + t];
        if (sv < v || (sv == v && sid < id)) { v = sv; id = sid; }
    }
    const float4* xp = (const float4*)(x   + (size_t)t * DIM);
    const float4* qp = (const float4*)(icb + (size_t)id * DIM);
    const int l = threadIdx.x;
    const float4 xv = xp[l];
    const float4 qv = qp[l];
    float p0 = xv.x * xv.x + xv.y * xv.y + xv.z * xv.z + xv.w * xv.w;
    float p1 = qv.x * qv.x + qv.y * qv.y + qv.z * qv.z + qv.w * qv.w;
    float p2 = xv.x * qv.x + xv.y * qv.y + xv.z * qv.z + xv.w * qv.w;
#pragma unroll
    for (int o = 1; o < 64; o <<= 1) {
        p0 += __shfl_xor(p0, o);
        p1 += __shfl_xor(p1, o);
        p2 += __shfl_xor(p2, o);
    }
    __shared__ float r0[2], r1[2], r2[2];
    const int w = threadIdx.x >> 6;
    if ((threadIdx.x & 63) == 0) { r0[w] = p0; r1[w] = p1; r2[w] = p2; }
    __syncthreads();
    const float sx2 = r0[0] + r0[1];
    const float sq2 = r1[0] + r1[1];
    const float sxq = r2[0] + r2[1];

    const float ns  = sqrtf(sx2);
    const float nt  = sqrtf(sq2);
    const float nsc = fmaxf(ns, EPSV);
    const float ntc = fmaxf(nt, EPSV);
    const float xu  = sx2 / nsc;
    const float xqh = sxq / ntc;
    const float xw0 = xu + xqh;
    const float w0n2 = sx2 / (nsc * nsc) + 2.f * sxq / (nsc * ntc) + sq2 / (ntc * ntc);
    const float w0nc = fmaxf(sqrtf(w0n2), EPSV);
    const float coefW = 2.f * xw0 / (w0nc * w0nc);
    const float coefQ = 2.f * xu / ntc;
    const float scale = nt / nsc;
    const float cx = scale * (1.f - coefW / nsc);
    const float cq = scale * (coefQ - coefW / ntc);

    float4 ov;
    ov.x = cx * xv.x + cq * qv.x;
    ov.y = cx * xv.y + cq * qv.y;
    ov.z = cx * xv.z + cq * qv.z;
    ov.w = cx * xv.w + cq * qv.w;
    ((float4*)(out_q + (size_t)t * DIM))[l] = ov;

    if (threadIdx.x == 0) {
        out_idx[t] = (float)id;
        const float se = sx2 - 2.f * sxq + sq2;
        atomicAdd(lossacc, se);
    }
}

// ---------------------------------------------------------------- launch
extern "C" void kernel_launch(void* const* d_in, const int* in_sizes, int n_in,
                              void* d_out, int out_size, void* d_ws, size_t ws_size,
                              hipStream_t stream) {
    const float* x  = (const float*)d_in[0];
    const float* cb = (const float*)d_in[1];
    const float* W1 = (const float*)d_in[2];
    const float* b1 = (const float*)d_in[3];
    const float* W2 = (const float*)d_in[4];
    const float* b2 = (const float*)d_in[5];

    char* ws = (char*)d_ws;
    float* h    = (float*)ws;                                      // 16.78 MB
    float* icb  = h + (size_t)CSIZE * DIM;                         // 16.78 MB
    unsigned short* W1Thi = (unsigned short*)(icb + (size_t)CSIZE * DIM);
    unsigned short* W1Tlo = W1Thi + (size_t)DIM * CDIM;            // 0.26 MB both
    unsigned short* W2Thi = W1Tlo + (size_t)DIM * CDIM;
    unsigned short* W2Tlo = W2Thi + (size_t)DIM * DIM;             // 1.05 MB both
    float* rn2  = (float*)(W2Tlo + (size_t)DIM * DIM);             // 32 KB
    float* pval = rn2 + CSIZE;                                     // 16*NTOK f32
    int*   pidx = (int*)(pval + (size_t)NSLICE2 * NTOK);           // 16*NTOK i32
    float* lossacc = (float*)(pidx + (size_t)NSLICE2 * NTOK);

    // code splits overlay h (h is dead after k_gemm2 consumed it)
    unsigned short* chi = (unsigned short*)h;
    unsigned short* clo = chi + (size_t)CSIZE * DIM;

    // x splits overlay d_out's out_q region (dead until k_epi writes it)
    unsigned short* xhi = (unsigned short*)d_out;
    unsigned short* xlo = xhi + (size_t)NTOK * DIM;

    float* out_q    = (float*)d_out;
    float* out_idx  = out_q + (size_t)NTOK * DIM;
    float* out_loss = out_idx + NTOK;

    k_zero<<<1, 1, 0, stream>>>(lossacc);
    k_split<<<(NTOK * DIM / 4) / 256, 256, 0, stream>>>(x, xhi, xlo, NTOK * DIM / 4);
    k_splitT<<<dim3(DIM / 32, CDIM / 32), 256, 0, stream>>>(W1, W1Thi, W1Tlo, CDIM, DIM);
    k_splitT<<<dim3(DIM / 32, DIM / 32), 256, 0, stream>>>(W2, W2Thi, W2Tlo, DIM, DIM);
    k_gemm<CDIM, false><<<dim3(CSIZE / 128, DIM / 128), 256, 0, stream>>>(cb, W1Thi, W1Tlo, b1, nullptr, h);
    k_gemm<DIM, true><<<dim3(CSIZE / 128, DIM / 128), 256, 0, stream>>>(h, W2Thi, W2Tlo, b2, h, icb);
    k_split<<<(CSIZE * DIM / 4) / 256, 256, 0, stream>>>(icb, chi, clo, CSIZE * DIM / 4);
    k_rn2<<<CSIZE / 4, 256, 0, stream>>>(icb, rn2);
    k_dist<<<dim3(NTOK / 256, NSLICE), 256, 0, stream>>>(xhi, xlo, chi, clo, rn2, pval, pidx);
    k_epi<<<NTOK, 128, 0, stream>>>(x, icb, pval, pidx, out_q, out_idx, lossacc);
    k_fin<<<1, 1, 0, stream>>>(lossacc, out_loss);
}

// Round 5
// 530.396 us; speedup vs baseline: 7.4465x; 1.3390x over previous
//
#include <hip/hip_runtime.h>
#include <math.h>

#define DIM   512
#define CDIM  128
#define CSIZE 8192
#define NTOK  16384          // 4 * 4096
#define EPSV  1e-6f
#define NSLICE 16            // k_dist grid.y code slices (grid 1024 -> 3 blocks/CU)

#define SELU_SCALE 1.0507009873554805f
#define SELU_ALPHA 1.6732632423543772f

typedef __bf16 bf16x8 __attribute__((ext_vector_type(8)));
typedef float  f32x4  __attribute__((ext_vector_type(4)));
typedef unsigned short u16x8 __attribute__((ext_vector_type(8)));

__device__ __forceinline__ float selu_f(float v) {
    return SELU_SCALE * (v > 0.f ? v : SELU_ALPHA * expm1f(v));
}

// RNE float -> bf16 bits
__device__ __forceinline__ unsigned short b16(float f) {
    unsigned u = __float_as_uint(f);
    u += 0x7FFFu + ((u >> 16) & 1u);
    return (unsigned short)(u >> 16);
}
__device__ __forceinline__ float b2f(unsigned short h) {
    return __uint_as_float(((unsigned)h) << 16);
}

// LDS byte-swizzle involution (verified 0 bank conflicts, rounds 3-4)
__device__ __forceinline__ unsigned SWZ(unsigned b) {
    return b ^ (((b >> 6) & 14u) << 3);
}

#define GLOAD16(g, l) __builtin_amdgcn_global_load_lds( \
    (const __attribute__((address_space(1))) void*)(g),  \
    (__attribute__((address_space(3))) void*)(l), 16, 0, 0)

// ---------------------------------------------------------------- init / fin
__global__ __launch_bounds__(256) void k_init(float* __restrict__ rn2,
                                              float* __restrict__ lossacc) {
    const int i = blockIdx.x * 256 + threadIdx.x;
    if (i < CSIZE) rn2[i] = 0.f;
    if (i < 64)    lossacc[i] = 0.f;
}

__global__ void k_fin(const float* __restrict__ lossacc, float* __restrict__ out_loss) {
    float v = lossacc[threadIdx.x];   // 64 threads
#pragma unroll
    for (int o = 1; o < 64; o <<= 1) v += __shfl_xor(v, o);
    if (threadIdx.x == 0)
        out_loss[0] = 1.25f * v / (float)((size_t)NTOK * DIM);
}

// ---------------------------------------------------------------- split f32 -> bf16 hi/lo (x)
__global__ __launch_bounds__(256) void k_split(const float* __restrict__ in,
                                               unsigned short* __restrict__ hi,
                                               unsigned short* __restrict__ lo,
                                               int n4) {
    const int i = blockIdx.x * 256 + threadIdx.x;
    if (i >= n4) return;
    const float4 v = ((const float4*)in)[i];
    const unsigned short h0 = b16(v.x), h1 = b16(v.y), h2 = b16(v.z), h3 = b16(v.w);
    const unsigned short l0 = b16(v.x - b2f(h0));
    const unsigned short l1 = b16(v.y - b2f(h1));
    const unsigned short l2 = b16(v.z - b2f(h2));
    const unsigned short l3 = b16(v.w - b2f(h3));
    ((ushort4*)hi)[i] = make_ushort4(h0, h1, h2, h3);
    ((ushort4*)lo)[i] = make_ushort4(l0, l1, l2, l3);
}

// ---------------------------------------------------------------- transpose + split: W[K,N] -> WT hi/lo [N,K]
__global__ __launch_bounds__(256) void k_splitT(const float* __restrict__ W,
                                                unsigned short* __restrict__ Thi,
                                                unsigned short* __restrict__ Tlo,
                                                int K, int N) {
    __shared__ float t[32][33];
    const int tx = threadIdx.x & 31, ty = threadIdx.x >> 5;   // 32 x 8
    const int n0 = blockIdx.x * 32, k0 = blockIdx.y * 32;
#pragma unroll
    for (int i = 0; i < 4; ++i)
        t[ty + i * 8][tx] = W[(size_t)(k0 + ty + i * 8) * N + n0 + tx];
    __syncthreads();
#pragma unroll
    for (int i = 0; i < 4; ++i) {
        const int n = n0 + ty + i * 8, k = k0 + tx;
        const float v = t[tx][ty + i * 8];
        const unsigned short h = b16(v);
        Thi[(size_t)n * K + k] = h;
        Tlo[(size_t)n * K + k] = b16(v - b2f(h));
    }
}

// ---------------------------------------------------------------- MFMA GEMM (split-bf16, 3-term)
// Tile 128(m) x 64(n), 4 waves of 64x32. A reg-staged (f32 -> selu? -> split ->
// swizzled ds_write); B via gload_lds (linear dest + SWZ source); reads SWZ'd.
// OUT_SPLIT=false: out = acc + bias (f32, gemm1 -> h).
// OUT_SPLIT=true : v = acc + bias + res; emit split bf16 hi/lo + rn2 atomics (gemm2).
template<int KTOT, bool OUT_SPLIT>
__global__ __launch_bounds__(256) void k_gemm(const float* __restrict__ A,
                                              const unsigned short* __restrict__ BThi,
                                              const unsigned short* __restrict__ BTlo,
                                              const float* __restrict__ bias,
                                              const float* __restrict__ res,
                                              float* __restrict__ outF,
                                              unsigned short* __restrict__ outHi,
                                              unsigned short* __restrict__ outLo,
                                              float* __restrict__ rn2) {
    __shared__ __align__(16) unsigned char smem[24576];   // AH 8K | AL 8K | BH 4K | BL 4K
    const int tid = threadIdx.x;
    const int wave = tid >> 6, lane = tid & 63;
    const int l15 = lane & 15, l4 = lane >> 4;
    const int m0 = blockIdx.x * 128, n0 = blockIdx.y * 64;
    const int wm0 = (wave >> 1) * 64, wn0 = (wave & 1) * 32;

    // B staging source offset (4KB tile, one round: chunk p = tid*16)
    const unsigned LB = SWZ((unsigned)tid * 16u);
    const int soffB = (int)(LB >> 6) * KTOT + (int)((LB >> 4) & 3) * 8;

    // fragment read offsets (mi/ni stride +1024)
    const unsigned ra0 = SWZ((unsigned)((wm0 + l15) * 64 + l4 * 16));
    const unsigned rb0 = SWZ((unsigned)((wn0 + l15) * 64 + l4 * 16));

    f32x4 acc[4][2];
#pragma unroll
    for (int a = 0; a < 4; ++a)
#pragma unroll
        for (int b = 0; b < 2; ++b) acc[a][b] = (f32x4)(0.f);

    for (int k0 = 0; k0 < KTOT; k0 += 32) {
        __syncthreads();
        // B: global_load_lds, linear dest (wave w covers bytes [w*1024,(w+1)*1024))
        GLOAD16(BThi + (size_t)n0 * KTOT + k0 + soffB, smem + 16384 + wave * 1024);
        GLOAD16(BTlo + (size_t)n0 * KTOT + k0 + soffB, smem + 20480 + wave * 1024);
        // A: reg-stage f32 -> (selu) -> split -> ds_write at SWZ(linear)
#pragma unroll
        for (int r = 0; r < 2; ++r) {
            const unsigned g = (unsigned)(tid + r * 256) * 16u;   // byte in [128][64B]
            const int grow = (int)(g >> 6), gel = (int)((g >> 4) & 3) * 8;
            const float4 v0 = *(const float4*)(A + (size_t)(m0 + grow) * KTOT + k0 + gel);
            const float4 v1 = *(const float4*)(A + (size_t)(m0 + grow) * KTOT + k0 + gel + 4);
            float s[8] = {v0.x, v0.y, v0.z, v0.w, v1.x, v1.y, v1.z, v1.w};
            u16x8 hv, lv;
#pragma unroll
            for (int j = 0; j < 8; ++j) {
                const float sv = OUT_SPLIT ? selu_f(s[j]) : s[j];
                const unsigned short hb = b16(sv);
                hv[j] = hb;
                lv[j] = b16(sv - b2f(hb));
            }
            const unsigned d = SWZ(g);
            *(u16x8*)(smem + d) = hv;
            *(u16x8*)(smem + 8192 + d) = lv;
        }
        __syncthreads();

        bf16x8 bh[2], bl[2];
#pragma unroll
        for (int ni = 0; ni < 2; ++ni) {
            bh[ni] = *(const bf16x8*)(smem + 16384 + rb0 + ni * 1024);
            bl[ni] = *(const bf16x8*)(smem + 20480 + rb0 + ni * 1024);
        }
#pragma unroll
        for (int mi = 0; mi < 4; ++mi) {
            const bf16x8 ah = *(const bf16x8*)(smem + ra0 + mi * 1024);
            const bf16x8 al = *(const bf16x8*)(smem + 8192 + ra0 + mi * 1024);
#pragma unroll
            for (int ni = 0; ni < 2; ++ni) {
                acc[mi][ni] = __builtin_amdgcn_mfma_f32_16x16x32_bf16(ah, bh[ni], acc[mi][ni], 0, 0, 0);
                acc[mi][ni] = __builtin_amdgcn_mfma_f32_16x16x32_bf16(ah, bl[ni], acc[mi][ni], 0, 0, 0);
                acc[mi][ni] = __builtin_amdgcn_mfma_f32_16x16x32_bf16(al, bh[ni], acc[mi][ni], 0, 0, 0);
            }
        }
    }
    // epilogue: C layout col = lane&15, row = (lane>>4)*4 + reg
#pragma unroll
    for (int mi = 0; mi < 4; ++mi)
#pragma unroll
        for (int rr = 0; rr < 4; ++rr) {
            const int m = m0 + wm0 + mi * 16 + l4 * 4 + rr;
            float s2 = 0.f;
#pragma unroll
            for (int ni = 0; ni < 2; ++ni) {
                const int n = n0 + wn0 + ni * 16 + l15;
                float v = acc[mi][ni][rr] + bias[n];
                if constexpr (OUT_SPLIT) {
                    v += res[(size_t)m * DIM + n];
                    const unsigned short hb = b16(v);
                    outHi[(size_t)m * DIM + n] = hb;
                    outLo[(size_t)m * DIM + n] = b16(v - b2f(hb));
                    s2 = fmaf(v, v, s2);
                } else {
                    outF[(size_t)m * DIM + n] = v;
                }
            }
            if constexpr (OUT_SPLIT) {
#pragma unroll
                for (int o = 1; o < 16; o <<= 1) s2 += __shfl_xor(s2, o);
                if (l15 == 0) atomicAdd(&rn2[m], s2);
            }
        }
}

// ---------------------------------------------------------------- MFMA distance + partial argmin
// Block: 256 tokens x 512 codes (4 n-tiles of 128). 4 waves (2x2), each 128x64.
// Col-half waves combine via LDS at the end -> one slice per blockIdx.y.
// d2' = rn2[c] - 2*(xh.ch + xh.cl + xl.ch), mfma_f32_16x16x32_bf16.
// LDS 48KB: AH[256][32]@0 16K, AL@16384, BH[128][32]@32768 8K, BL@40960.
// Linear gload_lds dest + SWZ'd global source + SWZ'd ds_read (both-sides rule).
__global__ __launch_bounds__(256, 2) void k_dist(const unsigned short* __restrict__ xh,
                                                 const unsigned short* __restrict__ xl,
                                                 const unsigned short* __restrict__ ch,
                                                 const unsigned short* __restrict__ cl,
                                                 const float* __restrict__ rn2,
                                                 float* __restrict__ pval,
                                                 int*   __restrict__ pidx) {
    __shared__ __align__(16) unsigned char smem[49152];
    const int tid  = threadIdx.x;
    const int wave = tid >> 6, lane = tid & 63;
    const int l15 = lane & 15, l4 = lane >> 4;
    const int m0   = blockIdx.x * 256;
    const int wm0  = (wave >> 1) * 128;    // wave row offset in tile
    const int wn0  = (wave & 1) * 64;      // wave col offset in tile

    // staging source offset (round 0); round r adds r*64*DIM (SWZ mask r-independent)
    const unsigned LS = SWZ((unsigned)tid * 16u);
    const int soff0 = (int)(LS >> 6) * DIM + (int)((LS >> 4) & 3) * 8;

    // fragment read offsets; mi/ni strides are +1024 bytes (mask mi-independent)
    const unsigned ra0 = SWZ((unsigned)((wm0 + l15) * 64 + l4 * 16));
    const unsigned rb0 = SWZ((unsigned)((wn0 + l15) * 64 + l4 * 16));

    float bestv[8][4];
    int   besti[8][4];
#pragma unroll
    for (int a = 0; a < 8; ++a)
#pragma unroll
        for (int b = 0; b < 4; ++b) { bestv[a][b] = 3.0e38f; besti[a][b] = 0; }

    const unsigned short* xhb = xh + (size_t)m0 * DIM;
    const unsigned short* xlb = xl + (size_t)m0 * DIM;
    const int cbase = blockIdx.y * (CSIZE / NSLICE);

    for (int nt = 0; nt < (CSIZE / NSLICE) / 128; ++nt) {
        const int n0 = cbase + nt * 128;
        const unsigned short* chb = ch + (size_t)n0 * DIM;
        const unsigned short* clb = cl + (size_t)n0 * DIM;

        f32x4 acc[8][4];
#pragma unroll
        for (int a = 0; a < 8; ++a)
#pragma unroll
            for (int b = 0; b < 4; ++b) acc[a][b] = (f32x4)(0.f);

        for (int k0 = 0; k0 < DIM; k0 += 32) {
            __syncthreads();   // previous tiles fully consumed
            const int sA = soff0 + k0;
#pragma unroll
            for (int r = 0; r < 4; ++r) {
                GLOAD16(xhb + sA + r * 64 * DIM, smem + 0     + r * 4096 + wave * 1024);
                GLOAD16(xlb + sA + r * 64 * DIM, smem + 16384 + r * 4096 + wave * 1024);
            }
#pragma unroll
            for (int r = 0; r < 2; ++r) {
                GLOAD16(chb + sA + r * 64 * DIM, smem + 32768 + r * 4096 + wave * 1024);
                GLOAD16(clb + sA + r * 64 * DIM, smem + 40960 + r * 4096 + wave * 1024);
            }
            __syncthreads();   // vmcnt drained before barrier: tiles ready

            bf16x8 bh[4], bl[4];
#pragma unroll
            for (int ni = 0; ni < 4; ++ni) {
                bh[ni] = *(const bf16x8*)(smem + 32768 + rb0 + ni * 1024);
                bl[ni] = *(const bf16x8*)(smem + 40960 + rb0 + ni * 1024);
            }
#pragma unroll
            for (int mi = 0; mi < 8; ++mi) {
                const bf16x8 ah = *(const bf16x8*)(smem + ra0 + mi * 1024);
                const bf16x8 al = *(const bf16x8*)(smem + 16384 + ra0 + mi * 1024);
#pragma unroll
                for (int ni = 0; ni < 4; ++ni) {
                    acc[mi][ni] = __builtin_amdgcn_mfma_f32_16x16x32_bf16(ah, bh[ni], acc[mi][ni], 0, 0, 0);
                    acc[mi][ni] = __builtin_amdgcn_mfma_f32_16x16x32_bf16(ah, bl[ni], acc[mi][ni], 0, 0, 0);
                    acc[mi][ni] = __builtin_amdgcn_mfma_f32_16x16x32_bf16(al, bh[ni], acc[mi][ni], 0, 0, 0);
                }
            }
        }

        // fold this n-tile into per-lane running best (d2 minus per-token ||x||^2)
#pragma unroll
        for (int ni = 0; ni < 4; ++ni) {
            const int n = n0 + wn0 + ni * 16 + l15;
            const float r = rn2[n];
#pragma unroll
            for (int mi = 0; mi < 8; ++mi)
#pragma unroll
                for (int rr = 0; rr < 4; ++rr) {
                    const float v = fmaf(-2.f, acc[mi][ni][rr], r);
                    if (v < bestv[mi][rr]) { bestv[mi][rr] = v; besti[mi][rr] = n; }
                }
        }
    }

    // reduce across 16 column-lanes, deposit per-wave results in LDS
    __syncthreads();                                  // all smem reads complete
    float* vbuf = (float*)smem;                       // [2][256]
    int*   ibuf = (int*)(smem + 2048);                // [2][256]
#pragma unroll
    for (int mi = 0; mi < 8; ++mi)
#pragma unroll
        for (int rr = 0; rr < 4; ++rr) {
            float v = bestv[mi][rr];
            int   id = besti[mi][rr];
#pragma unroll
            for (int o = 1; o < 16; o <<= 1) {
                const float ov = __shfl_xor(v, o);
                const int   oid = __shfl_xor(id, o);
                if (ov < v || (ov == v && oid < id)) { v = ov; id = oid; }
            }
            if (l15 == 0) {
                const int ml = wm0 + mi * 16 + l4 * 4 + rr;
                vbuf[(wave & 1) * 256 + ml] = v;
                ibuf[(wave & 1) * 256 + ml] = id;
            }
        }
    __syncthreads();
    // combine the two column halves; one writer per (slice, token)
    {
        const int ml = tid;                           // 0..255
        float v0 = vbuf[ml], v1 = vbuf[256 + ml];
        int   i0 = ibuf[ml], i1 = ibuf[256 + ml];
        if (v1 < v0 || (v1 == v0 && i1 < i0)) { v0 = v1; i0 = i1; }
        pval[(size_t)blockIdx.y * NTOK + m0 + ml] = v0;
        pidx[(size_t)blockIdx.y * NTOK + m0 + ml] = i0;
    }
}

// ---------------------------------------------------------------- epilogue: argmin, gather(reconstruct), rotate, loss
// 4 tokens per block, one wave per token. Loss into 64 distributed slots.
__global__ __launch_bounds__(256) void k_epi(const float* __restrict__ x,
                                             const unsigned short* __restrict__ chi,
                                             const unsigned short* __restrict__ clo,
                                             const float* __restrict__ pval,
                                             const int*   __restrict__ pidx,
                                             float* __restrict__ out_q,
                                             float* __restrict__ out_idx,
                                             float* __restrict__ lossacc) {
    const int wave = threadIdx.x >> 6, lane = threadIdx.x & 63;
    const int t = blockIdx.x * 4 + wave;

    float v = 3.0e38f; int id = 0;
    if (lane < NSLICE) {
        v  = pval[(size_t)lane * NTOK + t];
        id = pidx[(size_t)lane * NTOK + t];
    }
#pragma unroll
    for (int o = 1; o < 16; o <<= 1) {
        const float ov = __shfl_xor(v, o);
        const int   oid = __shfl_xor(id, o);
        if (ov < v || (ov == v && oid < id)) { v = ov; id = oid; }
    }
    id = __shfl(id, 0);

    const float4* xp = (const float4*)(x + (size_t)t * DIM);
    const float4 xv0 = xp[lane * 2];
    const float4 xv1 = xp[lane * 2 + 1];
    const u16x8 hv = *(const u16x8*)(chi + (size_t)id * DIM + lane * 8);
    const u16x8 lv = *(const u16x8*)(clo + (size_t)id * DIM + lane * 8);
    float q[8], xs[8] = {xv0.x, xv0.y, xv0.z, xv0.w, xv1.x, xv1.y, xv1.z, xv1.w};
#pragma unroll
    for (int j = 0; j < 8; ++j) q[j] = b2f(hv[j]) + b2f(lv[j]);

    float p0 = 0.f, p1 = 0.f, p2 = 0.f;
#pragma unroll
    for (int j = 0; j < 8; ++j) {
        p0 = fmaf(xs[j], xs[j], p0);
        p1 = fmaf(q[j], q[j], p1);
        p2 = fmaf(xs[j], q[j], p2);
    }
#pragma unroll
    for (int o = 1; o < 64; o <<= 1) {
        p0 += __shfl_xor(p0, o);
        p1 += __shfl_xor(p1, o);
        p2 += __shfl_xor(p2, o);
    }
    const float sx2 = p0, sq2 = p1, sxq = p2;

    const float ns  = sqrtf(sx2);
    const float nt  = sqrtf(sq2);
    const float nsc = fmaxf(ns, EPSV);
    const float ntc = fmaxf(nt, EPSV);
    const float xu  = sx2 / nsc;
    const float xqh = sxq / ntc;
    const float xw0 = xu + xqh;
    const float w0n2 = sx2 / (nsc * nsc) + 2.f * sxq / (nsc * ntc) + sq2 / (ntc * ntc);
    const float w0nc = fmaxf(sqrtf(w0n2), EPSV);
    const float coefW = 2.f * xw0 / (w0nc * w0nc);
    const float coefQ = 2.f * xu / ntc;
    const float scale = nt / nsc;
    const float cx = scale * (1.f - coefW / nsc);
    const float cq = scale * (coefQ - coefW / ntc);

    float4 ov0, ov1;
    ov0.x = cx * xs[0] + cq * q[0];  ov0.y = cx * xs[1] + cq * q[1];
    ov0.z = cx * xs[2] + cq * q[2];  ov0.w = cx * xs[3] + cq * q[3];
    ov1.x = cx * xs[4] + cq * q[4];  ov1.y = cx * xs[5] + cq * q[5];
    ov1.z = cx * xs[6] + cq * q[6];  ov1.w = cx * xs[7] + cq * q[7];
    ((float4*)(out_q + (size_t)t * DIM))[lane * 2]     = ov0;
    ((float4*)(out_q + (size_t)t * DIM))[lane * 2 + 1] = ov1;

    __shared__ float sew[4];
    if (lane == 0) {
        out_idx[t] = (float)id;
        sew[wave] = sx2 - 2.f * sxq + sq2;
    }
    __syncthreads();
    if (threadIdx.x == 0) {
        const float se = sew[0] + sew[1] + sew[2] + sew[3];
        atomicAdd(lossacc + (blockIdx.x & 63), se);
    }
}

// ---------------------------------------------------------------- launch
extern "C" void kernel_launch(void* const* d_in, const int* in_sizes, int n_in,
                              void* d_out, int out_size, void* d_ws, size_t ws_size,
                              hipStream_t stream) {
    const float* x  = (const float*)d_in[0];
    const float* cb = (const float*)d_in[1];
    const float* W1 = (const float*)d_in[2];
    const float* b1 = (const float*)d_in[3];
    const float* W2 = (const float*)d_in[4];
    const float* b2 = (const float*)d_in[5];

    char* ws = (char*)d_ws;
    float* h = (float*)ws;                                         // 16.78 MB (gemm1 out)
    unsigned short* chi = (unsigned short*)(h + (size_t)CSIZE * DIM);   // 8.39 MB
    unsigned short* clo = chi + (size_t)CSIZE * DIM;               // 8.39 MB
    unsigned short* W1Thi = clo + (size_t)CSIZE * DIM;
    unsigned short* W1Tlo = W1Thi + (size_t)DIM * CDIM;
    unsigned short* W2Thi = W1Tlo + (size_t)DIM * CDIM;
    unsigned short* W2Tlo = W2Thi + (size_t)DIM * DIM;
    float* rn2  = (float*)(W2Tlo + (size_t)DIM * DIM);             // 32 KB
    float* pval = rn2 + CSIZE;                                     // 16*NTOK f32
    int*   pidx = (int*)(pval + (size_t)NSLICE * NTOK);            // 16*NTOK i32
    float* lossacc = (float*)(pidx + (size_t)NSLICE * NTOK);       // 64 f32

    // x splits overlay d_out's out_q region (dead until k_epi writes it)
    unsigned short* xhi = (unsigned short*)d_out;
    unsigned short* xlo = xhi + (size_t)NTOK * DIM;

    float* out_q    = (float*)d_out;
    float* out_idx  = out_q + (size_t)NTOK * DIM;
    float* out_loss = out_idx + NTOK;

    k_init<<<(CSIZE + 255) / 256, 256, 0, stream>>>(rn2, lossacc);
    k_split<<<(NTOK * DIM / 4) / 256, 256, 0, stream>>>(x, xhi, xlo, NTOK * DIM / 4);
    k_splitT<<<dim3(DIM / 32, CDIM / 32), 256, 0, stream>>>(W1, W1Thi, W1Tlo, CDIM, DIM);
    k_splitT<<<dim3(DIM / 32, DIM / 32), 256, 0, stream>>>(W2, W2Thi, W2Tlo, DIM, DIM);
    k_gemm<CDIM, false><<<dim3(CSIZE / 128, DIM / 64), 256, 0, stream>>>(
        cb, W1Thi, W1Tlo, b1, nullptr, h, nullptr, nullptr, nullptr);
    k_gemm<DIM, true><<<dim3(CSIZE / 128, DIM / 64), 256, 0, stream>>>(
        h, W2Thi, W2Tlo, b2, h, nullptr, chi, clo, rn2);
    k_dist<<<dim3(NTOK / 256, NSLICE), 256, 0, stream>>>(xhi, xlo, chi, clo, rn2, pval, pidx);
    k_epi<<<NTOK / 4, 256, 0, stream>>>(x, chi, clo, pval, pidx, out_q, out_idx, lossacc);
    k_fin<<<1, 64, 0, stream>>>(lossacc, out_loss);
}

// Round 6
// 485.467 us; speedup vs baseline: 8.1357x; 1.0925x over previous
//
#include <hip/hip_runtime.h>
#include <math.h>

#define DIM   512
#define CDIM  128
#define CSIZE 8192
#define NTOK  16384          // 4 * 4096
#define EPSV  1e-6f
#define NSLICE 8             // k_dist grid.y code slices

#define SELU_SCALE 1.0507009873554805f
#define SELU_ALPHA 1.6732632423543772f

typedef __bf16 bf16x8 __attribute__((ext_vector_type(8)));
typedef float  f32x4  __attribute__((ext_vector_type(4)));
typedef unsigned short u16x8 __attribute__((ext_vector_type(8)));

__device__ __forceinline__ float selu_f(float v) {
    return SELU_SCALE * (v > 0.f ? v : SELU_ALPHA * expm1f(v));
}

// RNE float -> bf16 bits
__device__ __forceinline__ unsigned short b16(float f) {
    unsigned u = __float_as_uint(f);
    u += 0x7FFFu + ((u >> 16) & 1u);
    return (unsigned short)(u >> 16);
}
__device__ __forceinline__ float b2f(unsigned short h) {
    return __uint_as_float(((unsigned)h) << 16);
}

// LDS byte-swizzle involution (verified 0 bank conflicts, rounds 3-5)
__device__ __forceinline__ unsigned SWZ(unsigned b) {
    return b ^ (((b >> 6) & 14u) << 3);
}

#define GLOAD16(g, l) __builtin_amdgcn_global_load_lds( \
    (const __attribute__((address_space(1))) void*)(g),  \
    (__attribute__((address_space(3))) void*)(l), 16, 0, 0)

// ---------------------------------------------------------------- init / fin
__global__ __launch_bounds__(256) void k_init(float* __restrict__ rn2,
                                              float* __restrict__ lossacc) {
    const int i = blockIdx.x * 256 + threadIdx.x;
    if (i < CSIZE) rn2[i] = 0.f;
    if (i < 64)    lossacc[i] = 0.f;
}

__global__ void k_fin(const float* __restrict__ lossacc, float* __restrict__ out_loss) {
    float v = lossacc[threadIdx.x];   // 64 threads
#pragma unroll
    for (int o = 1; o < 64; o <<= 1) v += __shfl_xor(v, o);
    if (threadIdx.x == 0)
        out_loss[0] = 1.25f * v / (float)((size_t)NTOK * DIM);
}

// ---------------------------------------------------------------- split f32 -> bf16 hi/lo (x)
__global__ __launch_bounds__(256) void k_split(const float* __restrict__ in,
                                               unsigned short* __restrict__ hi,
                                               unsigned short* __restrict__ lo,
                                               int n4) {
    const int i = blockIdx.x * 256 + threadIdx.x;
    if (i >= n4) return;
    const float4 v = ((const float4*)in)[i];
    const unsigned short h0 = b16(v.x), h1 = b16(v.y), h2 = b16(v.z), h3 = b16(v.w);
    const unsigned short l0 = b16(v.x - b2f(h0));
    const unsigned short l1 = b16(v.y - b2f(h1));
    const unsigned short l2 = b16(v.z - b2f(h2));
    const unsigned short l3 = b16(v.w - b2f(h3));
    ((ushort4*)hi)[i] = make_ushort4(h0, h1, h2, h3);
    ((ushort4*)lo)[i] = make_ushort4(l0, l1, l2, l3);
}

// ---------------------------------------------------------------- transpose + split: W[K,N] -> WT hi/lo [N,K]
__global__ __launch_bounds__(256) void k_splitT(const float* __restrict__ W,
                                                unsigned short* __restrict__ Thi,
                                                unsigned short* __restrict__ Tlo,
                                                int K, int N) {
    __shared__ float t[32][33];
    const int tx = threadIdx.x & 31, ty = threadIdx.x >> 5;   // 32 x 8
    const int n0 = blockIdx.x * 32, k0 = blockIdx.y * 32;
#pragma unroll
    for (int i = 0; i < 4; ++i)
        t[ty + i * 8][tx] = W[(size_t)(k0 + ty + i * 8) * N + n0 + tx];
    __syncthreads();
#pragma unroll
    for (int i = 0; i < 4; ++i) {
        const int n = n0 + ty + i * 8, k = k0 + tx;
        const float v = t[tx][ty + i * 8];
        const unsigned short h = b16(v);
        Thi[(size_t)n * K + k] = h;
        Tlo[(size_t)n * K + k] = b16(v - b2f(h));
    }
}

// ---------------------------------------------------------------- MFMA GEMM (split-bf16, 3-term)
// Tile 128(m) x 64(n), 4 waves of 64x32. A reg-staged (f32 -> selu? -> split ->
// swizzled ds_write); B via gload_lds (linear dest + SWZ source); reads SWZ'd.
// OUT_SPLIT=false: out = acc + bias (f32, gemm1 -> h).
// OUT_SPLIT=true : v = acc + bias + res; emit split bf16 hi/lo + rn2 atomics (gemm2).
template<int KTOT, bool OUT_SPLIT>
__global__ __launch_bounds__(256) void k_gemm(const float* __restrict__ A,
                                              const unsigned short* __restrict__ BThi,
                                              const unsigned short* __restrict__ BTlo,
                                              const float* __restrict__ bias,
                                              const float* __restrict__ res,
                                              float* __restrict__ outF,
                                              unsigned short* __restrict__ outHi,
                                              unsigned short* __restrict__ outLo,
                                              float* __restrict__ rn2) {
    __shared__ __align__(16) unsigned char smem[24576];   // AH 8K | AL 8K | BH 4K | BL 4K
    const int tid = threadIdx.x;
    const int wave = tid >> 6, lane = tid & 63;
    const int l15 = lane & 15, l4 = lane >> 4;
    const int m0 = blockIdx.x * 128, n0 = blockIdx.y * 64;
    const int wm0 = (wave >> 1) * 64, wn0 = (wave & 1) * 32;

    // B staging source offset (4KB tile, one round: chunk p = tid*16)
    const unsigned LB = SWZ((unsigned)tid * 16u);
    const int soffB = (int)(LB >> 6) * KTOT + (int)((LB >> 4) & 3) * 8;

    // fragment read offsets (mi/ni stride +1024)
    const unsigned ra0 = SWZ((unsigned)((wm0 + l15) * 64 + l4 * 16));
    const unsigned rb0 = SWZ((unsigned)((wn0 + l15) * 64 + l4 * 16));

    f32x4 acc[4][2];
#pragma unroll
    for (int a = 0; a < 4; ++a)
#pragma unroll
        for (int b = 0; b < 2; ++b) acc[a][b] = (f32x4)(0.f);

    for (int k0 = 0; k0 < KTOT; k0 += 32) {
        __syncthreads();
        // B: global_load_lds, linear dest (wave w covers bytes [w*1024,(w+1)*1024))
        GLOAD16(BThi + (size_t)n0 * KTOT + k0 + soffB, smem + 16384 + wave * 1024);
        GLOAD16(BTlo + (size_t)n0 * KTOT + k0 + soffB, smem + 20480 + wave * 1024);
        // A: reg-stage f32 -> (selu) -> split -> ds_write at SWZ(linear)
#pragma unroll
        for (int r = 0; r < 2; ++r) {
            const unsigned g = (unsigned)(tid + r * 256) * 16u;   // byte in [128][64B]
            const int grow = (int)(g >> 6), gel = (int)((g >> 4) & 3) * 8;
            const float4 v0 = *(const float4*)(A + (size_t)(m0 + grow) * KTOT + k0 + gel);
            const float4 v1 = *(const float4*)(A + (size_t)(m0 + grow) * KTOT + k0 + gel + 4);
            float s[8] = {v0.x, v0.y, v0.z, v0.w, v1.x, v1.y, v1.z, v1.w};
            u16x8 hv, lv;
#pragma unroll
            for (int j = 0; j < 8; ++j) {
                const float sv = OUT_SPLIT ? selu_f(s[j]) : s[j];
                const unsigned short hb = b16(sv);
                hv[j] = hb;
                lv[j] = b16(sv - b2f(hb));
            }
            const unsigned d = SWZ(g);
            *(u16x8*)(smem + d) = hv;
            *(u16x8*)(smem + 8192 + d) = lv;
        }
        __syncthreads();

        bf16x8 bh[2], bl[2];
#pragma unroll
        for (int ni = 0; ni < 2; ++ni) {
            bh[ni] = *(const bf16x8*)(smem + 16384 + rb0 + ni * 1024);
            bl[ni] = *(const bf16x8*)(smem + 20480 + rb0 + ni * 1024);
        }
#pragma unroll
        for (int mi = 0; mi < 4; ++mi) {
            const bf16x8 ah = *(const bf16x8*)(smem + ra0 + mi * 1024);
            const bf16x8 al = *(const bf16x8*)(smem + 8192 + ra0 + mi * 1024);
#pragma unroll
            for (int ni = 0; ni < 2; ++ni) {
                acc[mi][ni] = __builtin_amdgcn_mfma_f32_16x16x32_bf16(ah, bh[ni], acc[mi][ni], 0, 0, 0);
                acc[mi][ni] = __builtin_amdgcn_mfma_f32_16x16x32_bf16(ah, bl[ni], acc[mi][ni], 0, 0, 0);
                acc[mi][ni] = __builtin_amdgcn_mfma_f32_16x16x32_bf16(al, bh[ni], acc[mi][ni], 0, 0, 0);
            }
        }
    }
    // epilogue: C layout col = lane&15, row = (lane>>4)*4 + reg
#pragma unroll
    for (int mi = 0; mi < 4; ++mi)
#pragma unroll
        for (int rr = 0; rr < 4; ++rr) {
            const int m = m0 + wm0 + mi * 16 + l4 * 4 + rr;
            float s2 = 0.f;
#pragma unroll
            for (int ni = 0; ni < 2; ++ni) {
                const int n = n0 + wn0 + ni * 16 + l15;
                float v = acc[mi][ni][rr] + bias[n];
                if constexpr (OUT_SPLIT) {
                    v += res[(size_t)m * DIM + n];
                    const unsigned short hb = b16(v);
                    outHi[(size_t)m * DIM + n] = hb;
                    outLo[(size_t)m * DIM + n] = b16(v - b2f(hb));
                    s2 = fmaf(v, v, s2);
                } else {
                    outF[(size_t)m * DIM + n] = v;
                }
            }
            if constexpr (OUT_SPLIT) {
#pragma unroll
                for (int o = 1; o < 16; o <<= 1) s2 += __shfl_xor(s2, o);
                if (l15 == 0) atomicAdd(&rn2[m], s2);
            }
        }
}

// ---------------------------------------------------------------- MFMA distance + partial argmin
// Block: 256 tokens x 1024 codes (4 n-tiles of 256). 8 waves (4m x 2n), each
// wave 64 tok x 128 codes. DOUBLE-BUFFERED LDS (2 x 64KB), T3-min schedule:
// per K-step: STAGE(next -> buf^1) issued FIRST, then ds_read+MFMA on buf,
// then ONE __syncthreads() (compiler drains vmcnt(0) before s_barrier ->
// staged data ready; buffer overwritten next iter was fully read before the
// PREVIOUS barrier -> race-free). Stage latency hides under the MFMA phase.
// d2' = rn2[c] - 2*(xh.ch + xh.cl + xl.ch), mfma_f32_16x16x32_bf16.
// Buf layout (per 64KB): AH[256][32]@0 | AL@16384 | BH[256][32]@32768 | BL@49152.
// Linear gload_lds dest + SWZ'd global source + SWZ'd ds_read (both-sides rule).
__global__ __launch_bounds__(512, 2) void k_dist(const unsigned short* __restrict__ xh,
                                                 const unsigned short* __restrict__ xl,
                                                 const unsigned short* __restrict__ ch,
                                                 const unsigned short* __restrict__ cl,
                                                 const float* __restrict__ rn2,
                                                 float* __restrict__ pval,
                                                 int*   __restrict__ pidx) {
    __shared__ __align__(16) unsigned char smem[131072];
    const int tid  = threadIdx.x;
    const int wave = tid >> 6, lane = tid & 63;
    const int l15 = lane & 15, l4 = lane >> 4;
    const int m0   = blockIdx.x * 256;
    const int wm0  = (wave >> 1) * 64;     // wave row offset (4 row-groups)
    const int wn0  = (wave & 1) * 128;     // wave col offset (2 col-halves)

    // staging source offset: chunk p = tid*16 (rows 0..127); round r adds
    // r*8192 bytes = 128 rows (bit 13: SWZ mask bits 7-9 unaffected)
    const unsigned LS = SWZ((unsigned)tid * 16u);
    const int soff0 = (int)(LS >> 6) * DIM + (int)((LS >> 4) & 3) * 8;

    // fragment read offsets; mi/ni strides +1024 (SWZ mask depends on row bits
    // 1-3 only -> +16 rows preserves it)
    const unsigned ra0 = SWZ((unsigned)((wm0 + l15) * 64 + l4 * 16));
    const unsigned rb0 = SWZ((unsigned)((wn0 + l15) * 64 + l4 * 16));

    const unsigned short* xhb = xh + (size_t)m0 * DIM;
    const unsigned short* xlb = xl + (size_t)m0 * DIM;
    const int cbase = blockIdx.y * (CSIZE / NSLICE);

    constexpr int NT   = (CSIZE / NSLICE) / 256;   // 4 n-tiles
    constexpr int TOTI = NT * (DIM / 32);          // 64 K-step iterations

    auto stage = [&](int iter, unsigned bufbase) {
        const int nt2 = iter >> 4;
        const int k0n = (iter & 15) * 32;
        const int sA  = soff0 + k0n;
        const size_t cb0 = (size_t)(cbase + nt2 * 256) * DIM;
#pragma unroll
        for (int r = 0; r < 2; ++r) {
            GLOAD16(xhb + sA + r * 128 * DIM,      smem + bufbase + 0     + r * 8192 + wave * 1024);
            GLOAD16(xlb + sA + r * 128 * DIM,      smem + bufbase + 16384 + r * 8192 + wave * 1024);
            GLOAD16(ch + cb0 + sA + r * 128 * DIM, smem + bufbase + 32768 + r * 8192 + wave * 1024);
            GLOAD16(cl + cb0 + sA + r * 128 * DIM, smem + bufbase + 49152 + r * 8192 + wave * 1024);
        }
    };

    float bestv[4][4];
    int   besti[4][4];
#pragma unroll
    for (int a = 0; a < 4; ++a)
#pragma unroll
        for (int b = 0; b < 4; ++b) { bestv[a][b] = 3.0e38f; besti[a][b] = 0; }

    // prologue: stage iteration 0 into buf0, drain, go
    stage(0, 0u);
    __syncthreads();
    unsigned cur = 0;

    for (int nt = 0; nt < NT; ++nt) {
        f32x4 acc[4][8];
#pragma unroll
        for (int a = 0; a < 4; ++a)
#pragma unroll
            for (int b = 0; b < 8; ++b) acc[a][b] = (f32x4)(0.f);

        for (int ks = 0; ks < 16; ++ks) {
            const int iter = nt * 16 + ks;
            if (iter + 1 < TOTI) stage(iter + 1, (cur ^ 1u) * 65536u);

            const unsigned char* base = smem + cur * 65536u;
            bf16x8 ah[4], al[4];
#pragma unroll
            for (int mi = 0; mi < 4; ++mi) {
                ah[mi] = *(const bf16x8*)(base + ra0 + mi * 1024);
                al[mi] = *(const bf16x8*)(base + 16384 + ra0 + mi * 1024);
            }
#pragma unroll
            for (int ni = 0; ni < 8; ++ni) {
                const bf16x8 bh = *(const bf16x8*)(base + 32768 + rb0 + ni * 1024);
                const bf16x8 bl = *(const bf16x8*)(base + 49152 + rb0 + ni * 1024);
#pragma unroll
                for (int mi = 0; mi < 4; ++mi) {
                    acc[mi][ni] = __builtin_amdgcn_mfma_f32_16x16x32_bf16(ah[mi], bh, acc[mi][ni], 0, 0, 0);
                    acc[mi][ni] = __builtin_amdgcn_mfma_f32_16x16x32_bf16(ah[mi], bl, acc[mi][ni], 0, 0, 0);
                    acc[mi][ni] = __builtin_amdgcn_mfma_f32_16x16x32_bf16(al[mi], bh, acc[mi][ni], 0, 0, 0);
                }
            }
            __syncthreads();   // drains this iter's stage; next buf ready
            cur ^= 1u;
        }

        // fold this n-tile into per-lane running best (d2 minus ||x||^2 const)
        const int n0 = cbase + nt * 256;
#pragma unroll
        for (int ni = 0; ni < 8; ++ni) {
            const int n = n0 + wn0 + ni * 16 + l15;
            const float r = rn2[n];
#pragma unroll
            for (int mi = 0; mi < 4; ++mi)
#pragma unroll
                for (int rr = 0; rr < 4; ++rr) {
                    const float v = fmaf(-2.f, acc[mi][ni][rr], r);
                    if (v < bestv[mi][rr]) { bestv[mi][rr] = v; besti[mi][rr] = n; }
                }
        }
    }

    // reduce across 16 column-lanes, deposit per-wave results in LDS
    __syncthreads();                                  // all smem traffic complete
    float* vbuf = (float*)smem;                       // [2][256]
    int*   ibuf = (int*)(smem + 2048);                // [2][256]
#pragma unroll
    for (int mi = 0; mi < 4; ++mi)
#pragma unroll
        for (int rr = 0; rr < 4; ++rr) {
            float v = bestv[mi][rr];
            int   id = besti[mi][rr];
#pragma unroll
            for (int o = 1; o < 16; o <<= 1) {
                const float ov = __shfl_xor(v, o);
                const int   oid = __shfl_xor(id, o);
                if (ov < v || (ov == v && oid < id)) { v = ov; id = oid; }
            }
            if (l15 == 0) {
                const int ml = wm0 + mi * 16 + l4 * 4 + rr;   // token-in-block
                vbuf[(wave & 1) * 256 + ml] = v;
                ibuf[(wave & 1) * 256 + ml] = id;
            }
        }
    __syncthreads();
    // combine the two column halves; one writer per (slice, token)
    if (tid < 256) {
        const int ml = tid;
        float v0 = vbuf[ml], v1 = vbuf[256 + ml];
        int   i0 = ibuf[ml], i1 = ibuf[256 + ml];
        if (v1 < v0 || (v1 == v0 && i1 < i0)) { v0 = v1; i0 = i1; }
        pval[(size_t)blockIdx.y * NTOK + m0 + ml] = v0;
        pidx[(size_t)blockIdx.y * NTOK + m0 + ml] = i0;
    }
}

// ---------------------------------------------------------------- epilogue: argmin, gather(reconstruct), rotate, loss
// 4 tokens per block, one wave per token. Loss into 64 distributed slots.
__global__ __launch_bounds__(256) void k_epi(const float* __restrict__ x,
                                             const unsigned short* __restrict__ chi,
                                             const unsigned short* __restrict__ clo,
                                             const float* __restrict__ pval,
                                             const int*   __restrict__ pidx,
                                             float* __restrict__ out_q,
                                             float* __restrict__ out_idx,
                                             float* __restrict__ lossacc) {
    const int wave = threadIdx.x >> 6, lane = threadIdx.x & 63;
    const int t = blockIdx.x * 4 + wave;

    float v = 3.0e38f; int id = 0;
    if (lane < NSLICE) {
        v  = pval[(size_t)lane * NTOK + t];
        id = pidx[(size_t)lane * NTOK + t];
    }
#pragma unroll
    for (int o = 1; o < 16; o <<= 1) {
        const float ov = __shfl_xor(v, o);
        const int   oid = __shfl_xor(id, o);
        if (ov < v || (ov == v && oid < id)) { v = ov; id = oid; }
    }
    id = __shfl(id, 0);

    const float4* xp = (const float4*)(x + (size_t)t * DIM);
    const float4 xv0 = xp[lane * 2];
    const float4 xv1 = xp[lane * 2 + 1];
    const u16x8 hv = *(const u16x8*)(chi + (size_t)id * DIM + lane * 8);
    const u16x8 lv = *(const u16x8*)(clo + (size_t)id * DIM + lane * 8);
    float q[8], xs[8] = {xv0.x, xv0.y, xv0.z, xv0.w, xv1.x, xv1.y, xv1.z, xv1.w};
#pragma unroll
    for (int j = 0; j < 8; ++j) q[j] = b2f(hv[j]) + b2f(lv[j]);

    float p0 = 0.f, p1 = 0.f, p2 = 0.f;
#pragma unroll
    for (int j = 0; j < 8; ++j) {
        p0 = fmaf(xs[j], xs[j], p0);
        p1 = fmaf(q[j], q[j], p1);
        p2 = fmaf(xs[j], q[j], p2);
    }
#pragma unroll
    for (int o = 1; o < 64; o <<= 1) {
        p0 += __shfl_xor(p0, o);
        p1 += __shfl_xor(p1, o);
        p2 += __shfl_xor(p2, o);
    }
    const float sx2 = p0, sq2 = p1, sxq = p2;

    const float ns  = sqrtf(sx2);
    const float nt  = sqrtf(sq2);
    const float nsc = fmaxf(ns, EPSV);
    const float ntc = fmaxf(nt, EPSV);
    const float xu  = sx2 / nsc;
    const float xqh = sxq / ntc;
    const float xw0 = xu + xqh;
    const float w0n2 = sx2 / (nsc * nsc) + 2.f * sxq / (nsc * ntc) + sq2 / (ntc * ntc);
    const float w0nc = fmaxf(sqrtf(w0n2), EPSV);
    const float coefW = 2.f * xw0 / (w0nc * w0nc);
    const float coefQ = 2.f * xu / ntc;
    const float scale = nt / nsc;
    const float cx = scale * (1.f - coefW / nsc);
    const float cq = scale * (coefQ - coefW / ntc);

    float4 ov0, ov1;
    ov0.x = cx * xs[0] + cq * q[0];  ov0.y = cx * xs[1] + cq * q[1];
    ov0.z = cx * xs[2] + cq * q[2];  ov0.w = cx * xs[3] + cq * q[3];
    ov1.x = cx * xs[4] + cq * q[4];  ov1.y = cx * xs[5] + cq * q[5];
    ov1.z = cx * xs[6] + cq * q[6];  ov1.w = cx * xs[7] + cq * q[7];
    ((float4*)(out_q + (size_t)t * DIM))[lane * 2]     = ov0;
    ((float4*)(out_q + (size_t)t * DIM))[lane * 2 + 1] = ov1;

    __shared__ float sew[4];
    if (lane == 0) {
        out_idx[t] = (float)id;
        sew[wave] = sx2 - 2.f * sxq + sq2;
    }
    __syncthreads();
    if (threadIdx.x == 0) {
        const float se = sew[0] + sew[1] + sew[2] + sew[3];
        atomicAdd(lossacc + (blockIdx.x & 63), se);
    }
}

// ---------------------------------------------------------------- launch
extern "C" void kernel_launch(void* const* d_in, const int* in_sizes, int n_in,
                              void* d_out, int out_size, void* d_ws, size_t ws_size,
                              hipStream_t stream) {
    const float* x  = (const float*)d_in[0];
    const float* cb = (const float*)d_in[1];
    const float* W1 = (const float*)d_in[2];
    const float* b1 = (const float*)d_in[3];
    const float* W2 = (const float*)d_in[4];
    const float* b2 = (const float*)d_in[5];

    char* ws = (char*)d_ws;
    float* h = (float*)ws;                                         // 16.78 MB (gemm1 out)
    unsigned short* chi = (unsigned short*)(h + (size_t)CSIZE * DIM);   // 8.39 MB
    unsigned short* clo = chi + (size_t)CSIZE * DIM;               // 8.39 MB
    unsigned short* W1Thi = clo + (size_t)CSIZE * DIM;
    unsigned short* W1Tlo = W1Thi + (size_t)DIM * CDIM;
    unsigned short* W2Thi = W1Tlo + (size_t)DIM * CDIM;
    unsigned short* W2Tlo = W2Thi + (size_t)DIM * DIM;
    float* rn2  = (float*)(W2Tlo + (size_t)DIM * DIM);             // 32 KB
    float* pval = rn2 + CSIZE;                                     // 8*NTOK f32
    int*   pidx = (int*)(pval + (size_t)NSLICE * NTOK);            // 8*NTOK i32
    float* lossacc = (float*)(pidx + (size_t)NSLICE * NTOK);       // 64 f32

    // x splits overlay d_out's out_q region (dead until k_epi writes it)
    unsigned short* xhi = (unsigned short*)d_out;
    unsigned short* xlo = xhi + (size_t)NTOK * DIM;

    float* out_q    = (float*)d_out;
    float* out_idx  = out_q + (size_t)NTOK * DIM;
    float* out_loss = out_idx + NTOK;

    k_init<<<(CSIZE + 255) / 256, 256, 0, stream>>>(rn2, lossacc);
    k_split<<<(NTOK * DIM / 4) / 256, 256, 0, stream>>>(x, xhi, xlo, NTOK * DIM / 4);
    k_splitT<<<dim3(DIM / 32, CDIM / 32), 256, 0, stream>>>(W1, W1Thi, W1Tlo, CDIM, DIM);
    k_splitT<<<dim3(DIM / 32, DIM / 32), 256, 0, stream>>>(W2, W2Thi, W2Tlo, DIM, DIM);
    k_gemm<CDIM, false><<<dim3(CSIZE / 128, DIM / 64), 256, 0, stream>>>(
        cb, W1Thi, W1Tlo, b1, nullptr, h, nullptr, nullptr, nullptr);
    k_gemm<DIM, true><<<dim3(CSIZE / 128, DIM / 64), 256, 0, stream>>>(
        h, W2Thi, W2Tlo, b2, h, nullptr, chi, clo, rn2);
    k_dist<<<dim3(NTOK / 256, NSLICE), 512, 0, stream>>>(xhi, xlo, chi, clo, rn2, pval, pidx);
    k_epi<<<NTOK / 4, 256, 0, stream>>>(x, chi, clo, pval, pidx, out_q, out_idx, lossacc);
    k_fin<<<1, 64, 0, stream>>>(lossacc, out_loss);
}